// Round 5
// baseline (1978.943 us; speedup 1.0000x reference)
//
#include <hip/hip_runtime.h>
#include <math.h>

#define TT 512
#define BB 512
#define CC 32
#define CIN 33
#define HH 128
#define EPSF 1e-12f
#define CH 8               // timesteps per gx-chunk staged in LDS (8 -> LDS fits 2 blocks/CU)
#define NCH (TT / CH)
#define RB 2               // batch rows per block
#define HSP 160            // hs row stride (halves): 320 B
#define GXP 520            // gx row stride (floats) per (k,row): 512 data + 8 pad

typedef _Float16 half8 __attribute__((ext_vector_type(8)));
typedef _Float16 half2v __attribute__((ext_vector_type(2)));
typedef float f32x4 __attribute__((ext_vector_type(4)));

#define MFMA16H(a, b, c) __builtin_amdgcn_mfma_f32_16x16x32_f16(a, b, c, 0, 0, 0)
// In-loop barrier: LDS visibility only (no vmcnt drain; staging loads stay in flight).
#define BARRIER() asm volatile("s_waitcnt lgkmcnt(0)\n\ts_barrier" ::: "memory")

__device__ __forceinline__ float fsig(float x) {
    return __builtin_amdgcn_rcpf(1.f + __expf(-x));
}
__device__ __forceinline__ float ftanh(float x) {
    return 1.f - 2.f * __builtin_amdgcn_rcpf(1.f + __expf(2.f * x));
}
// full-wave (64) sum via DPP; result valid on lane 63 ONLY.
__device__ __forceinline__ float wave_sum_dpp(float x) {
    x += __int_as_float(__builtin_amdgcn_update_dpp(0, __float_as_int(x), 0x111, 0xf, 0xf, true));
    x += __int_as_float(__builtin_amdgcn_update_dpp(0, __float_as_int(x), 0x112, 0xf, 0xf, true));
    x += __int_as_float(__builtin_amdgcn_update_dpp(0, __float_as_int(x), 0x114, 0xf, 0xf, true));
    x += __int_as_float(__builtin_amdgcn_update_dpp(0, __float_as_int(x), 0x118, 0xf, 0xf, true));
    x += __int_as_float(__builtin_amdgcn_update_dpp(0, __float_as_int(x), 0x142, 0xa, 0xf, true));
    x += __int_as_float(__builtin_amdgcn_update_dpp(0, __float_as_int(x), 0x143, 0xc, 0xf, true));
    return x;
}
// sum within each 16-lane row; result valid on lanes 15/31/47/63.
__device__ __forceinline__ float row_sum_dpp(float x) {
    x += __int_as_float(__builtin_amdgcn_update_dpp(0, __float_as_int(x), 0x111, 0xf, 0xf, true));
    x += __int_as_float(__builtin_amdgcn_update_dpp(0, __float_as_int(x), 0x112, 0xf, 0xf, true));
    x += __int_as_float(__builtin_amdgcn_update_dpp(0, __float_as_int(x), 0x114, 0xf, 0xf, true));
    x += __int_as_float(__builtin_amdgcn_update_dpp(0, __float_as_int(x), 0x118, 0xf, 0xf, true));
    return x;
}
// spin-load ws[t]: ws is 0xAA-poisoned each launch (sentinel). Relaxed order is
// sufficient; AGENT scope gives cross-XCD visibility. Iteration cap -> worst
// case is a wrong value, never a hang.
__device__ __forceinline__ float load_s(const float* p) {
    float v = __hip_atomic_load(p, __ATOMIC_RELAXED, __HIP_MEMORY_SCOPE_AGENT);
    for (int it = 0; it < 100000000 && __float_as_uint(v) == 0xAAAAAAAAu; ++it)
        v = __hip_atomic_load(p, __ATOMIC_RELAXED, __HIP_MEMORY_SCOPE_AGENT);
    return v;
}

// ---------------------------------------------------------------------------
// R23: R22's wave-specialized structure (verified -21%) + 2 blocks/CU.
// CH 16->8 shrinks gxs so LDS ~75 KB -> two co-resident blocks per CU;
// waves_per_eu(4,4) pins the 128-VGPR cap the R22 allocator already meets
// (R22 compiled to exactly 128 with zero spills). Each SIMD now hosts 2
// compute + 2 service waves from mutually unsynchronized blocks: one block's
// MFMA issue fills the other's ds_read/activation/barrier stalls (the ~1000
// cy/step latency R19/R21/R22 localized). Staging cadence within a chunk:
// k=0 load, k=2 spin, k=4 commit.
// ---------------------------------------------------------------------------
__global__ __attribute__((amdgpu_flat_work_group_size(512, 512), amdgpu_waves_per_eu(4, 4)))
void critic_fused(
    const float* __restrict__ x,
    const float* __restrict__ w_ih, const float* __restrict__ u_ih,
    const float* __restrict__ w_hh, const float* __restrict__ u_hh,
    const float* __restrict__ b_ih, const float* __restrict__ b_hh,
    const float* __restrict__ attn_w, const float* __restrict__ attn_b,
    const float* __restrict__ fc_w, const float* __restrict__ u_fc,
    const float* __restrict__ fc_b,
    float* __restrict__ ws,
    float* __restrict__ out)
{
    const int tid = threadIdx.x;
    const int w   = tid >> 6;          // wave 0..7
    const int l   = tid & 63;          // lane
    const int m   = l & 15;            // A-row / B-col index
    const int q   = l >> 4;            // quad 0..3
    const int b0  = blockIdx.x * RB;
    const int sw  = w - 4;             // service wave id (valid for w>=4)
    const int col = 32 * (w & 3) + (l & 31);  // compute lane's h column
    const int row = l >> 5;            // compute lane's batch row
    const int sub = (l >> 4) & 1;      // compute lane's col-subtile

    // ---- LDS (~75 KB -> 2 blocks/CU) ----
    __shared__ float4 sSS[2][8][8];                         // std wave-partials per tt
    __shared__ float4 sQQ[2][8][8];
    __shared__ float stdp[2][8];                            // per-c4 std partials
    __shared__ float red[512];                              // sigma scratch
    __shared__ float vv[128];
    __shared__ float sigS[3];                               // sig_ih, sig_hh, sig_fc
    __shared__ __align__(16) _Float16 hs[2][RB][HSP];       // h planes
    __shared__ __align__(16) float gxs[2][CH][RB][GXP];     // gate-interleaved gates_x
    __shared__ __align__(8) float bcast[2][RB];             // beta per row
    __shared__ float Sf[RB];
    __shared__ float part[4][4];                            // FC partials

    // ===== Phase A loads issued FIRST (HBM latency hidden by phase B) =====
    const int c4 = tid & 7;       // c = c4*4 .. c4*4+3
    const int bs = tid >> 3;      // 64 groups of 8 batch rows
    float4 xa[2][8];
#pragma unroll
    for (int tt = 0; tt < 2; ++tt) {
        const int t = 2 * blockIdx.x + tt;
#pragma unroll
        for (int i = 0; i < 8; ++i)
            xa[tt][i] = *reinterpret_cast<const float4*>(
                x + ((size_t)(bs * 8 + i) * TT + t) * CC + c4 * 4);
    }

    // ===== sigma_hh projection in the loads' shadow (L2-bound) =====
    {
        const int c = tid & 127, qq = tid >> 7;
        const float* wp = w_hh + (size_t)(qq * 128) * HH + c;
        const float* up = u_hh + qq * 128;
        float a0 = 0.f, a1 = 0.f, a2 = 0.f, a3 = 0.f;
#pragma unroll 4
        for (int g = 0; g < 128; g += 4) {
            a0 = fmaf(wp[(size_t)(g + 0) * HH], up[g + 0], a0);
            a1 = fmaf(wp[(size_t)(g + 1) * HH], up[g + 1], a1);
            a2 = fmaf(wp[(size_t)(g + 2) * HH], up[g + 2], a2);
            a3 = fmaf(wp[(size_t)(g + 3) * HH], up[g + 3], a3);
        }
        red[tid] = (a0 + a1) + (a2 + a3);
    }

    // ===== Phase A reduction (registers already landed) =====
#pragma unroll
    for (int tt = 0; tt < 2; ++tt) {
        float4 S = make_float4(0.f, 0.f, 0.f, 0.f);
        float4 Q = make_float4(0.f, 0.f, 0.f, 0.f);
#pragma unroll
        for (int i = 0; i < 8; ++i) {
            float4 v = xa[tt][i];
            S.x += v.x; S.y += v.y; S.z += v.z; S.w += v.w;
            Q.x = fmaf(v.x, v.x, Q.x); Q.y = fmaf(v.y, v.y, Q.y);
            Q.z = fmaf(v.z, v.z, Q.z); Q.w = fmaf(v.w, v.w, Q.w);
        }
#pragma unroll
        for (int off = 8; off <= 32; off <<= 1) {
            S.x += __shfl_xor(S.x, off, 64); S.y += __shfl_xor(S.y, off, 64);
            S.z += __shfl_xor(S.z, off, 64); S.w += __shfl_xor(S.w, off, 64);
            Q.x += __shfl_xor(Q.x, off, 64); Q.y += __shfl_xor(Q.y, off, 64);
            Q.z += __shfl_xor(Q.z, off, 64); Q.w += __shfl_xor(Q.w, off, 64);
        }
        if (l < 8) { sSS[tt][w][c4] = S; sQQ[tt][w][c4] = Q; }
    }
    __syncthreads();   // publishes red[] (projection) + sSS/sQQ

    // disjoint groups: tid<128 -> vv combine; tid 384..399 -> std combine
    if (tid < 128) vv[tid] = red[tid] + red[tid + 128] + red[tid + 256] + red[tid + 384];
    if (tid >= 384 && tid < 400) {
        const int tt2 = (tid - 384) >> 3, cc = (tid - 384) & 7;
        float4 St = make_float4(0.f, 0.f, 0.f, 0.f);
        float4 Qt = make_float4(0.f, 0.f, 0.f, 0.f);
#pragma unroll
        for (int i = 0; i < 8; ++i) {
            float4 a = sSS[tt2][i][cc], b4 = sQQ[tt2][i][cc];
            St.x += a.x; St.y += a.y; St.z += a.z; St.w += a.w;
            Qt.x += b4.x; Qt.y += b4.y; Qt.z += b4.z; Qt.w += b4.w;
        }
        float st = 0.f;
#pragma unroll
        for (int i = 0; i < 4; ++i) {
            float s1 = (i == 0) ? St.x : (i == 1) ? St.y : (i == 2) ? St.z : St.w;
            float q1 = (i == 0) ? Qt.x : (i == 1) ? Qt.y : (i == 2) ? Qt.z : Qt.w;
            float mean = s1 / 512.0f;
            float var  = (q1 - 512.0f * mean * mean) / 511.0f;
            st += sqrtf(fmaxf(var, 0.f));
        }
        stdp[tt2][cc] = st;
    }
    __syncthreads();
    // tid 408/409: publish ws[t]; all: square vv for norm reduction
    if (tid >= 408 && tid < 410) {
        const int tt2 = tid - 408;
        float mm = 0.f;
#pragma unroll
        for (int i = 0; i < 8; ++i) mm += stdp[tt2][i];
        __hip_atomic_store(&ws[2 * blockIdx.x + tt2], mm / 32.0f, __ATOMIC_RELAXED,
                           __HIP_MEMORY_SCOPE_AGENT);
    }
    red[tid] = (tid < 128) ? vv[tid] * vv[tid] : 0.f;
    __syncthreads();

    // ===== sigma_hh: norm + W@v =====
    {
        for (int s = 64; s >= 1; s >>= 1) { if (tid < s) red[tid] += red[tid + s]; __syncthreads(); }
        const float nv = sqrtf(red[0]);
        __syncthreads();
        if (tid < 128) vv[tid] = vv[tid] / (nv + EPSF);
        __syncthreads();
        float sq = 0.f;
        float2 vl = *reinterpret_cast<const float2*>(&vv[2 * l]);
#pragma unroll 4
        for (int gi = 0; gi < 64; ++gi) {
            const int g = w * 64 + gi;
            float2 wl = *reinterpret_cast<const float2*>(&w_hh[(size_t)g * HH + 2 * l]);
            float p  = fmaf(wl.x, vl.x, wl.y * vl.y);
            float tot = wave_sum_dpp(p);
            sq = fmaf(tot, tot, sq);
        }
        if (l == 63) red[w] = sq;
        __syncthreads();
        if (tid == 0) {
            float ns2 = 0.f;
            for (int i = 0; i < 8; ++i) ns2 += red[i];
            sigS[1] = ns2 / (sqrtf(ns2) + EPSF);
        }
        __syncthreads();
    }
    // ===== sigma_ih =====
    {
        if (l < CIN) {
            float a0 = 0.f, a1 = 0.f;
#pragma unroll 4
            for (int gi = 0; gi < 64; gi += 2) {
                const int g = w * 64 + gi;
                a0 = fmaf(w_ih[(size_t)(g + 0) * CIN + l], u_ih[g + 0], a0);
                a1 = fmaf(w_ih[(size_t)(g + 1) * CIN + l], u_ih[g + 1], a1);
            }
            red[w * 64 + l] = a0 + a1;
        }
        __syncthreads();
        if (tid < CIN) {
            float v = 0.f;
#pragma unroll
            for (int i = 0; i < 8; ++i) v += red[i * 64 + tid];
            vv[tid] = v;
        }
        __syncthreads();
        if (tid == 0) {
            float n2 = 0.f;
            for (int i = 0; i < CIN; ++i) n2 += vv[i] * vv[i];
            red[400] = sqrtf(n2);
        }
        __syncthreads();
        const float nv = red[400];
        if (tid < CIN) vv[tid] = vv[tid] / (nv + EPSF);
        __syncthreads();
        float vl = (l < CIN) ? vv[l] : 0.f;
        float sq = 0.f;
#pragma unroll 4
        for (int gi = 0; gi < 64; ++gi) {
            const int g = w * 64 + gi;
            float p = (l < CIN) ? w_ih[(size_t)g * CIN + l] * vl : 0.f;
            float tot = wave_sum_dpp(p);
            sq = fmaf(tot, tot, sq);
        }
        if (l == 63) red[w] = sq;
        __syncthreads();
        if (tid == 0) {
            float ns2 = 0.f;
            for (int i = 0; i < 8; ++i) ns2 += red[i];
            sigS[0] = ns2 / (sqrtf(ns2) + EPSF);
        }
        __syncthreads();
    }
    // ===== sigma_fc =====
    {
        red[tid] = (tid < 128) ? fc_w[tid] * fc_w[tid] : 0.f;
        __syncthreads();
        for (int s = 64; s >= 1; s >>= 1) { if (tid < s) red[tid] += red[tid + s]; __syncthreads(); }
        if (tid == 0) {
            float nw2 = red[0];
            float u0  = u_fc[0];
            float nv  = fabsf(u0) * sqrtf(nw2);
            float wv  = u0 * nw2 / (nv + EPSF);
            sigS[2]   = wv * wv / (fabsf(wv) + EPSF);
        }
        __syncthreads();
    }
    const float rih = 1.f / sigS[0];
    const float rhh = 1.f / sigS[1];
    const float rfc = 1.f / sigS[2];
    const float attb = attn_b[0];

    // ================= Phase C: role-split weight conversion =================
    // compute (w<4): BREG[p][sub][kt] = Whh B-frags for cols 32w+16sub+m.
    // service (w>=4): BREG[p][sub][0] aliased as Wih B-frags for its cols.
    half8 BREG[4][2][4];
    float biasg[4][2], w32g[4][2];
    float fcwj = 0.f, aw0 = 0.f, aw1 = 0.f;
    f32x4 zero4 = (f32x4){0.f, 0.f, 0.f, 0.f};
    if (w < 4) {
#pragma unroll
        for (int p = 0; p < 4; ++p)
#pragma unroll
            for (int s = 0; s < 2; ++s) {
                const int g = 128 * p + 32 * w + 16 * s + m;
#pragma unroll
                for (int kt = 0; kt < 4; ++kt) {
                    const float* src = w_hh + (size_t)g * HH + kt * 32 + q * 8;
#pragma unroll
                    for (int i = 0; i < 8; ++i) BREG[p][s][kt][i] = (_Float16)(src[i] * rhh);
                }
            }
#pragma unroll
        for (int p = 0; p < 4; ++p)
#pragma unroll
            for (int s = 0; s < 2; ++s)
#pragma unroll
                for (int kt = 0; kt < 4; ++kt) asm volatile("" : "+v"(BREG[p][s][kt]));
        fcwj = fc_w[col] * rfc;
    } else {
#pragma unroll
        for (int p = 0; p < 4; ++p)
#pragma unroll
            for (int s = 0; s < 2; ++s) {
                const int g = 128 * p + 32 * sw + 16 * s + m;
                const float* src = w_ih + (size_t)g * CIN + q * 8;
#pragma unroll
                for (int i = 0; i < 8; ++i) BREG[p][s][0][i] = (_Float16)(src[i] * rih);
                w32g[p][s]  = w_ih[(size_t)g * CIN + 32] * rih;
                biasg[p][s] = b_ih[g] + b_hh[g];
                asm volatile("" : "+v"(BREG[p][s][0]));
                asm volatile("" : "+v"(biasg[p][s]), "+v"(w32g[p][s]));
            }
        aw0 = attn_w[2 * l];
        aw1 = attn_w[2 * l + 1];
    }
    asm volatile("" : "+v"(zero4));

    // ---- staging (CH=8): A-row (0..15) = (k,rr); lane m holds row m
    //      -> k = m>>1, rr = m&1. ----
#define STAGE_LOAD(t0_, xr_)                                                   \
    {                                                                          \
        const size_t base =                                                    \
            ((size_t)(b0 + (m & 1)) * TT + ((t0_) + (m >> 1))) * CC + q * 8;   \
        xr_[0] = *reinterpret_cast<const float4*>(x + base);                   \
        xr_[1] = *reinterpret_cast<const float4*>(x + base + 4);               \
    }

#define STAGE_SPIN(t0_, svr_)                                                  \
    {                                                                          \
        svr_[0] = load_s(&ws[(t0_) + 2 * q]);                                  \
        svr_[1] = load_s(&ws[(t0_) + 2 * q + 1]);                              \
    }

    // D row 4q+j -> k = 2q+(j>>1), rr = j&1. Lane writes gate-interleaved
    // f32x4 (bias + w32*std folded) for its service cols.
#define STAGE_COMMIT(nb_, xr_, svr_)                                           \
    {                                                                          \
        half8 af = {(_Float16)xr_[0].x, (_Float16)xr_[0].y,                    \
                    (_Float16)xr_[0].z, (_Float16)xr_[0].w,                    \
                    (_Float16)xr_[1].x, (_Float16)xr_[1].y,                    \
                    (_Float16)xr_[1].z, (_Float16)xr_[1].w};                   \
        _Pragma("unroll")                                                      \
        for (int s = 0; s < 2; ++s) {                                          \
            f32x4 s0 = MFMA16H(af, BREG[0][s][0], zero4);                      \
            f32x4 s1 = MFMA16H(af, BREG[1][s][0], zero4);                      \
            f32x4 s2 = MFMA16H(af, BREG[2][s][0], zero4);                      \
            f32x4 s3 = MFMA16H(af, BREG[3][s][0], zero4);                      \
            _Pragma("unroll")                                                  \
            for (int j = 0; j < 4; ++j) {                                      \
                const float sv = (j & 2) ? svr_[1] : svr_[0];                  \
                f32x4 gv;                                                      \
                gv[0] = s0[j] + fmaf(w32g[0][s], sv, biasg[0][s]);             \
                gv[1] = s1[j] + fmaf(w32g[1][s], sv, biasg[1][s]);             \
                gv[2] = s2[j] + fmaf(w32g[2][s], sv, biasg[2][s]);             \
                gv[3] = s3[j] + fmaf(w32g[3][s], sv, biasg[3][s]);             \
                *reinterpret_cast<f32x4*>(                                     \
                    &gxs[nb_][2 * q + (j >> 1)][j & 1]                         \
                        [(32 * sw + 16 * s + m) * 4]) = gv;                    \
            }                                                                  \
        }                                                                      \
    }

    // ================= Phase E: lstm main =================
    for (int i = tid; i < 2 * RB * HSP; i += 512) (&hs[0][0][0])[i] = (_Float16)0.f;

    float c_st = 0.f, P = 0.f, hprev = 0.f, hpp = 0.f;  // compute lanes
    float Sreg = 0.f;                                    // service 4,5 lane 63
    float4 xr[2];
    float svr[2];

    if (w >= 4) {   // chunk-0 staging (spins on ws published by all blocks)
        STAGE_LOAD(0, xr);
        STAGE_SPIN(0, svr);
        STAGE_COMMIT(0, xr, svr);
    }
    __syncthreads();

    for (int tc = 0; tc < NCH; ++tc) {
        const int cb  = tc & 1;
        const int t0n = (tc + 1) * CH;
#pragma unroll 2
        for (int k = 0; k < CH; ++k) {
            const int t  = tc * CH + k;
            const int hb = (t + 1) & 1;
            if (w < 4) {
                // ---------------- compute step ----------------
                half8 ah0 = *(const half8*)&hs[hb][m & 1][0 * 32 + q * 8];
                half8 ah1 = *(const half8*)&hs[hb][m & 1][1 * 32 + q * 8];
                half8 ah2 = *(const half8*)&hs[hb][m & 1][2 * 32 + q * 8];
                half8 ah3 = *(const half8*)&hs[hb][m & 1][3 * 32 + q * 8];
                f32x4 gx4 = *reinterpret_cast<const f32x4*>(&gxs[cb][k][row][col * 4]);
                if (t >= 2) P = fmaf(bcast[(t - 1) & 1][row], hpp, P);
                f32x4 c00 = MFMA16H(ah0, BREG[0][0][0], zero4);
                f32x4 c10 = MFMA16H(ah0, BREG[0][1][0], zero4);
                f32x4 c01 = MFMA16H(ah0, BREG[1][0][0], zero4);
                f32x4 c11 = MFMA16H(ah0, BREG[1][1][0], zero4);
                f32x4 c02 = MFMA16H(ah0, BREG[2][0][0], zero4);
                f32x4 c12 = MFMA16H(ah0, BREG[2][1][0], zero4);
                f32x4 c03 = MFMA16H(ah0, BREG[3][0][0], zero4);
                f32x4 c13 = MFMA16H(ah0, BREG[3][1][0], zero4);
                c00 = MFMA16H(ah1, BREG[0][0][1], c00);
                c10 = MFMA16H(ah1, BREG[0][1][1], c10);
                c01 = MFMA16H(ah1, BREG[1][0][1], c01);
                c11 = MFMA16H(ah1, BREG[1][1][1], c11);
                c02 = MFMA16H(ah1, BREG[2][0][1], c02);
                c12 = MFMA16H(ah1, BREG[2][1][1], c12);
                c03 = MFMA16H(ah1, BREG[3][0][1], c03);
                c13 = MFMA16H(ah1, BREG[3][1][1], c13);
                c00 = MFMA16H(ah2, BREG[0][0][2], c00);
                c10 = MFMA16H(ah2, BREG[0][1][2], c10);
                c01 = MFMA16H(ah2, BREG[1][0][2], c01);
                c11 = MFMA16H(ah2, BREG[1][1][2], c11);
                c02 = MFMA16H(ah2, BREG[2][0][2], c02);
                c12 = MFMA16H(ah2, BREG[2][1][2], c12);
                c03 = MFMA16H(ah2, BREG[3][0][2], c03);
                c13 = MFMA16H(ah2, BREG[3][1][2], c13);
                c00 = MFMA16H(ah3, BREG[0][0][3], c00);
                c10 = MFMA16H(ah3, BREG[0][1][3], c10);
                c01 = MFMA16H(ah3, BREG[1][0][3], c01);
                c11 = MFMA16H(ah3, BREG[1][1][3], c11);
                c02 = MFMA16H(ah3, BREG[2][0][3], c02);
                c12 = MFMA16H(ah3, BREG[2][1][3], c12);
                c03 = MFMA16H(ah3, BREG[3][0][3], c03);
                c13 = MFMA16H(ah3, BREG[3][1][3], c13);
                // D reg j holds batch row j&1; select reg by row, acc by sub.
                float g0 = (sub ? (row ? c10[1] : c10[0]) : (row ? c00[1] : c00[0])) + gx4[0];
                float g1 = (sub ? (row ? c11[1] : c11[0]) : (row ? c01[1] : c01[0])) + gx4[1];
                float g2 = (sub ? (row ? c12[1] : c12[0]) : (row ? c02[1] : c02[0])) + gx4[2];
                float g3 = (sub ? (row ? c13[1] : c13[0]) : (row ? c03[1] : c03[0])) + gx4[3];
                float ig = fsig(g0);
                float fg = fsig(g1);
                float gg = ftanh(g2);
                float og = fsig(g3);
                c_st = fmaf(fg, c_st, ig * gg);
                float hv = og * ftanh(c_st);
                hpp   = hprev;
                hprev = hv;
                hs[t & 1][row][col] = (_Float16)hv;
            } else {
                // ---------------- service step ----------------
                if (sw < 2 && t > 0) {
                    half2v hh = *(const half2v*)&hs[hb][sw][2 * l];
                    float dotp = fmaf(aw0, (float)hh[0], aw1 * (float)hh[1]);
                    float tot = wave_sum_dpp(dotp);
                    if (l == 63) {
                        float beta = __expf(tot + attb);
                        Sreg += beta;
                        bcast[t & 1][sw] = beta;
                    }
                }
                if (tc + 1 < NCH) {
                    if (k == 0) STAGE_LOAD(t0n, xr);
                    if (k == 2) STAGE_SPIN(t0n, svr);
                    if (k == 4) STAGE_COMMIT(cb ^ 1, xr, svr);
                }
            }
            BARRIER();
        }
    }

    // ---- epilogue ----
    if (w < 4) P = fmaf(bcast[1][row], hpp, P);
    if (w >= 4 && sw < 2) {
        half2v hh = *(const half2v*)&hs[1][sw][2 * l];
        float dotp = fmaf(aw0, (float)hh[0], aw1 * (float)hh[1]);
        float tot = wave_sum_dpp(dotp);
        if (l == 63) {
            float beta = __expf(tot + attb);
            Sreg += beta;
            bcast[0][sw] = beta;
            Sf[sw] = Sreg;
        }
    }
    __syncthreads();
    if (w < 4) {
        float Pv = fmaf(bcast[0][row], hprev, P);
        float v  = Pv * __builtin_amdgcn_rcpf(Sf[row]) * fcwj;
        float rs = row_sum_dpp(v);
        if ((l & 15) == 15) part[w][q] = rs;   // q: 0,1 -> row0 subtiles; 2,3 -> row1
    }
    __syncthreads();
    if (tid < RB) {
        float a = 0.f;
#pragma unroll
        for (int i = 0; i < 4; ++i) a += part[i][2 * tid] + part[i][2 * tid + 1];
        out[b0 + tid] = a + fc_b[0];
    }
}

// ---------------------------------------------------------------------------
extern "C" void kernel_launch(void* const* d_in, const int* in_sizes, int n_in,
                              void* d_out, int out_size, void* d_ws, size_t ws_size,
                              hipStream_t stream) {
    const float* x      = (const float*)d_in[0];
    const float* w_ih   = (const float*)d_in[1];
    const float* u_ih   = (const float*)d_in[2];
    const float* w_hh   = (const float*)d_in[3];
    const float* u_hh   = (const float*)d_in[4];
    const float* b_ih   = (const float*)d_in[5];
    const float* b_hh   = (const float*)d_in[6];
    const float* attn_w = (const float*)d_in[7];
    const float* attn_b = (const float*)d_in[8];
    const float* fc_w   = (const float*)d_in[9];
    const float* u_fc   = (const float*)d_in[10];
    const float* fc_b   = (const float*)d_in[11];
    float* ws  = (float*)d_ws;
    float* out = (float*)d_out;

    critic_fused<<<BB / RB, 512, 0, stream>>>(x, w_ih, u_ih, w_hh, u_hh, b_ih, b_hh,
                                              attn_w, attn_b, fc_w, u_fc, fc_b, ws, out);
}

// Round 7
// 623.971 us; speedup vs baseline: 3.1715x; 3.1715x over previous
//
#include <hip/hip_runtime.h>
#include <math.h>

#define TT 512
#define BB 512
#define CC 32
#define CIN 33
#define HH 128
#define EPSF 1e-12f
#define CH 16              // timesteps per gx-chunk staged in LDS
#define NCH (TT / CH)
#define HSP 160            // hs stride (halves)
#define GXP 520            // gx row stride (floats): 512 data + 8 pad

typedef _Float16 half8 __attribute__((ext_vector_type(8)));
typedef float f32x4 __attribute__((ext_vector_type(4)));

#define MFMA16H(a, b, c) __builtin_amdgcn_mfma_f32_16x16x32_f16(a, b, c, 0, 0, 0)
// In-loop barrier: LDS visibility only (no vmcnt drain; staging loads stay in flight).
#define BARRIER() asm volatile("s_waitcnt lgkmcnt(0)\n\ts_barrier" ::: "memory")

__device__ __forceinline__ float fsig(float x) {
    return __builtin_amdgcn_rcpf(1.f + __expf(-x));
}
__device__ __forceinline__ float ftanh(float x) {
    return 1.f - 2.f * __builtin_amdgcn_rcpf(1.f + __expf(2.f * x));
}
// full-wave (64) sum via DPP; result valid on lane 63 ONLY.
__device__ __forceinline__ float wave_sum_dpp(float x) {
    x += __int_as_float(__builtin_amdgcn_update_dpp(0, __float_as_int(x), 0x111, 0xf, 0xf, true));
    x += __int_as_float(__builtin_amdgcn_update_dpp(0, __float_as_int(x), 0x112, 0xf, 0xf, true));
    x += __int_as_float(__builtin_amdgcn_update_dpp(0, __float_as_int(x), 0x114, 0xf, 0xf, true));
    x += __int_as_float(__builtin_amdgcn_update_dpp(0, __float_as_int(x), 0x118, 0xf, 0xf, true));
    x += __int_as_float(__builtin_amdgcn_update_dpp(0, __float_as_int(x), 0x142, 0xa, 0xf, true));
    x += __int_as_float(__builtin_amdgcn_update_dpp(0, __float_as_int(x), 0x143, 0xc, 0xf, true));
    return x;
}
// spin-load ws[t]: ws is 0xAA-poisoned each launch (sentinel). Relaxed order is
// sufficient; AGENT scope gives cross-XCD visibility. Iteration cap -> worst
// case is a wrong value, never a hang.
__device__ __forceinline__ float load_s(const float* p) {
    float v = __hip_atomic_load(p, __ATOMIC_RELAXED, __HIP_MEMORY_SCOPE_AGENT);
    for (int it = 0; it < 100000000 && __float_as_uint(v) == 0xAAAAAAAAu; ++it)
        v = __hip_atomic_load(p, __ATOMIC_RELAXED, __HIP_MEMORY_SCOPE_AGENT);
    return v;
}

// ---------------------------------------------------------------------------
// R25 (= R24 + do/while macro fix): 512 blocks x 256 threads (4 waves), ONE
// batch row per block, ~70 KB LDS -> TWO co-resident blocks per CU
// (guaranteed: 512 = 256CU x 2, LDS 2x71<160, VGPR<=256 via waves_per_eu(2,2)
// -- the budget R20/R23's (4,4)=64-reg death avoided). The two blocks are
// mutually async: one block's MFMA stream fills the other's ds_read/act/
// barrier latency (the ~1000cy/step R19-R22 localized as the wall). Single
// row broadcast in all 16 MFMA A-rows; all 4 waves compute 128 gate-cols each
// (BREG 128 VGPR); attn logit = per-wave DPP partial in the act tail + 1-lane
// combine pipelined one step behind; staging folded into all waves at
// k=0/2/8 once per 16 steps.
// ---------------------------------------------------------------------------
__global__ __attribute__((amdgpu_flat_work_group_size(256, 256), amdgpu_waves_per_eu(2, 2)))
void critic_fused(
    const float* __restrict__ x,
    const float* __restrict__ w_ih, const float* __restrict__ u_ih,
    const float* __restrict__ w_hh, const float* __restrict__ u_hh,
    const float* __restrict__ b_ih, const float* __restrict__ b_hh,
    const float* __restrict__ attn_w, const float* __restrict__ attn_b,
    const float* __restrict__ fc_w, const float* __restrict__ u_fc,
    const float* __restrict__ fc_b,
    float* __restrict__ ws,
    float* __restrict__ out)
{
    const int tid = threadIdx.x;
    const int w   = tid >> 6;          // wave 0..3
    const int l   = tid & 63;          // lane
    const int m   = l & 15;            // MFMA col index
    const int q   = l >> 4;            // quad 0..3
    const int brow = blockIdx.x;       // batch row; ALSO the std timestep this block owns
    const int hcol = 32 * w + 16 * (q & 1) + m;   // this lane's h column (q,q+2 duplicate)

    // ---- LDS (~70 KB -> 2 blocks/CU) ----
    __shared__ float4 sSS[4][8];                            // std wave-partials
    __shared__ float4 sQQ[4][8];
    __shared__ float stdp[8];                               // per-c4 std partials
    __shared__ float red[256];                              // sigma scratch
    __shared__ float vv[128];
    __shared__ float sigS[3];                               // sig_ih, sig_hh, sig_fc
    __shared__ __align__(16) _Float16 hs[2][HSP];           // h planes (1 row)
    __shared__ __align__(16) float gxs[2][CH][GXP];         // gate-interleaved gates_x
    __shared__ float bcast[2];                              // beta per parity
    __shared__ float part[2][4];                            // attn partials per parity
    __shared__ float SfS;
    __shared__ float fcp[4];                                // FC partials

    // ===== Phase A loads issued FIRST (HBM latency hidden by phase B) =====
    const int c4 = tid & 7;       // c = c4*4 .. c4*4+3
    const int bs = tid >> 3;      // 32 groups of 16 batch rows
    float4 xa[16];
#pragma unroll
    for (int i = 0; i < 16; ++i)
        xa[i] = *reinterpret_cast<const float4*>(
            x + ((size_t)(bs * 16 + i) * TT + brow) * CC + c4 * 4);

    // ===== sigma_hh projection in the loads' shadow (L2-bound) =====
    {
        const int c = tid & 127, qq = tid >> 7;
        const float* wp = w_hh + (size_t)(qq * 256) * HH + c;
        const float* up = u_hh + qq * 256;
        float a0 = 0.f, a1 = 0.f, a2 = 0.f, a3 = 0.f;
#pragma unroll 4
        for (int g = 0; g < 256; g += 4) {
            a0 = fmaf(wp[(size_t)(g + 0) * HH], up[g + 0], a0);
            a1 = fmaf(wp[(size_t)(g + 1) * HH], up[g + 1], a1);
            a2 = fmaf(wp[(size_t)(g + 2) * HH], up[g + 2], a2);
            a3 = fmaf(wp[(size_t)(g + 3) * HH], up[g + 3], a3);
        }
        red[tid] = (a0 + a1) + (a2 + a3);
    }

    // ===== Phase A reduction (registers already landed) =====
    {
        float4 S = make_float4(0.f, 0.f, 0.f, 0.f);
        float4 Q = make_float4(0.f, 0.f, 0.f, 0.f);
#pragma unroll
        for (int i = 0; i < 16; ++i) {
            float4 v = xa[i];
            S.x += v.x; S.y += v.y; S.z += v.z; S.w += v.w;
            Q.x = fmaf(v.x, v.x, Q.x); Q.y = fmaf(v.y, v.y, Q.y);
            Q.z = fmaf(v.z, v.z, Q.z); Q.w = fmaf(v.w, v.w, Q.w);
        }
#pragma unroll
        for (int off = 8; off <= 32; off <<= 1) {
            S.x += __shfl_xor(S.x, off, 64); S.y += __shfl_xor(S.y, off, 64);
            S.z += __shfl_xor(S.z, off, 64); S.w += __shfl_xor(S.w, off, 64);
            Q.x += __shfl_xor(Q.x, off, 64); Q.y += __shfl_xor(Q.y, off, 64);
            Q.z += __shfl_xor(Q.z, off, 64); Q.w += __shfl_xor(Q.w, off, 64);
        }
        if (l < 8) { sSS[w][l] = S; sQQ[w][l] = Q; }
    }
    __syncthreads();   // publishes red[] (projection) + sSS/sQQ

    // disjoint groups: tid<128 -> vv combine; tid 128..135 -> std combine
    if (tid < 128) vv[tid] = red[tid] + red[tid + 128];
    if (tid >= 128 && tid < 136) {
        const int cc = tid - 128;
        float4 St = make_float4(0.f, 0.f, 0.f, 0.f);
        float4 Qt = make_float4(0.f, 0.f, 0.f, 0.f);
#pragma unroll
        for (int i = 0; i < 4; ++i) {
            float4 a = sSS[i][cc], b4 = sQQ[i][cc];
            St.x += a.x; St.y += a.y; St.z += a.z; St.w += a.w;
            Qt.x += b4.x; Qt.y += b4.y; Qt.z += b4.z; Qt.w += b4.w;
        }
        float st = 0.f;
#pragma unroll
        for (int i = 0; i < 4; ++i) {
            float s1 = (i == 0) ? St.x : (i == 1) ? St.y : (i == 2) ? St.z : St.w;
            float q1 = (i == 0) ? Qt.x : (i == 1) ? Qt.y : (i == 2) ? Qt.z : Qt.w;
            float mean = s1 / 512.0f;
            float var  = (q1 - 512.0f * mean * mean) / 511.0f;
            st += sqrtf(fmaxf(var, 0.f));
        }
        stdp[cc] = st;
    }
    __syncthreads();
    // tid 136: publish ws[brow]; all: square vv for norm reduction
    if (tid == 136) {
        float mm = 0.f;
#pragma unroll
        for (int i = 0; i < 8; ++i) mm += stdp[i];
        __hip_atomic_store(&ws[brow], mm / 32.0f, __ATOMIC_RELAXED,
                           __HIP_MEMORY_SCOPE_AGENT);
    }
    red[tid] = (tid < 128) ? vv[tid] * vv[tid] : 0.f;
    __syncthreads();

    // ===== sigma_hh: norm + W@v =====
    {
        for (int s = 64; s >= 1; s >>= 1) { if (tid < s) red[tid] += red[tid + s]; __syncthreads(); }
        const float nv = sqrtf(red[0]);
        __syncthreads();
        if (tid < 128) vv[tid] = vv[tid] / (nv + EPSF);
        __syncthreads();
        float sq = 0.f;
        float2 vl = *reinterpret_cast<const float2*>(&vv[2 * l]);
#pragma unroll 4
        for (int gi = 0; gi < 128; ++gi) {
            const int g = w * 128 + gi;
            float2 wl = *reinterpret_cast<const float2*>(&w_hh[(size_t)g * HH + 2 * l]);
            float p  = fmaf(wl.x, vl.x, wl.y * vl.y);
            float tot = wave_sum_dpp(p);
            sq = fmaf(tot, tot, sq);
        }
        if (l == 63) red[w] = sq;
        __syncthreads();
        if (tid == 0) {
            float ns2 = red[0] + red[1] + red[2] + red[3];
            sigS[1] = ns2 / (sqrtf(ns2) + EPSF);
        }
        __syncthreads();
    }
    // ===== sigma_ih =====
    {
        if (l < CIN) {
            float a0 = 0.f, a1 = 0.f;
#pragma unroll 4
            for (int gi = 0; gi < 128; gi += 2) {
                const int g = w * 128 + gi;
                a0 = fmaf(w_ih[(size_t)(g + 0) * CIN + l], u_ih[g + 0], a0);
                a1 = fmaf(w_ih[(size_t)(g + 1) * CIN + l], u_ih[g + 1], a1);
            }
            red[w * 64 + l] = a0 + a1;
        }
        __syncthreads();
        if (tid < CIN) {
            float v = 0.f;
#pragma unroll
            for (int i = 0; i < 4; ++i) v += red[i * 64 + tid];
            vv[tid] = v;
        }
        __syncthreads();
        if (tid == 0) {
            float n2 = 0.f;
            for (int i = 0; i < CIN; ++i) n2 += vv[i] * vv[i];
            red[254] = sqrtf(n2);
        }
        __syncthreads();
        const float nv = red[254];
        if (tid < CIN) vv[tid] = vv[tid] / (nv + EPSF);
        __syncthreads();
        float vl = (l < CIN) ? vv[l] : 0.f;
        float sq = 0.f;
#pragma unroll 4
        for (int gi = 0; gi < 128; ++gi) {
            const int g = w * 128 + gi;
            float p = (l < CIN) ? w_ih[(size_t)g * CIN + l] * vl : 0.f;
            float tot = wave_sum_dpp(p);
            sq = fmaf(tot, tot, sq);
        }
        if (l == 63) red[w] = sq;
        __syncthreads();
        if (tid == 0) {
            float ns2 = red[0] + red[1] + red[2] + red[3];
            sigS[0] = ns2 / (sqrtf(ns2) + EPSF);
        }
        __syncthreads();
    }
    // ===== sigma_fc =====
    {
        red[tid] = (tid < 128) ? fc_w[tid] * fc_w[tid] : 0.f;
        __syncthreads();
        for (int s = 64; s >= 1; s >>= 1) { if (tid < s) red[tid] += red[tid + s]; __syncthreads(); }
        if (tid == 0) {
            float nw2 = red[0];
            float u0  = u_fc[0];
            float nv  = fabsf(u0) * sqrtf(nw2);
            float wv  = u0 * nw2 / (nv + EPSF);
            sigS[2]   = wv * wv / (fabsf(wv) + EPSF);
        }
        __syncthreads();
    }
    const float rih = 1.f / sigS[0];
    const float rhh = 1.f / sigS[1];
    const float rfc = 1.f / sigS[2];
    const float attb = attn_b[0];
    const float awj  = attn_w[hcol];
    const float fcwj = fc_w[hcol] * rfc;

    // ================= Phase C: Whh fragments (128 VGPR) =================
    // tile ct = 2*gate + jhi; gcol = 128*gate + 32*w + 16*jhi + m.
    half8 BREG[8][4];
#pragma unroll
    for (int ct = 0; ct < 8; ++ct) {
        const int gcol = 128 * (ct >> 1) + 32 * w + 16 * (ct & 1) + m;
#pragma unroll
        for (int kt = 0; kt < 4; ++kt) {
            const float* src = w_hh + (size_t)gcol * HH + kt * 32 + q * 8;
#pragma unroll
            for (int i = 0; i < 8; ++i) BREG[ct][kt][i] = (_Float16)(src[i] * rhh);
        }
    }
    f32x4 zero4 = (f32x4){0.f, 0.f, 0.f, 0.f};
#pragma unroll
    for (int ct = 0; ct < 8; ++ct)
#pragma unroll
        for (int kt = 0; kt < 4; ++kt) asm volatile("" : "+v"(BREG[ct][kt]));
    asm volatile("" : "+v"(zero4));

    // ---- staging: A-row m = timestep t0+m, channels q*8..q*8+7 ----
#define XLOAD(t0_)                                                             \
    do {                                                                       \
        const size_t base = ((size_t)brow * TT + (t0_) + m) * CC + q * 8;      \
        xr0 = *reinterpret_cast<const float4*>(x + base);                      \
        xr1 = *reinterpret_cast<const float4*>(x + base + 4);                  \
    } while (0)

    // batched issue, then individual spin check (steady state: 1 L2 latency)
#define WSPIN(t0_)                                                             \
    do {                                                                       \
        svr[0] = __hip_atomic_load(&ws[(t0_) + 4 * q + 0], __ATOMIC_RELAXED, __HIP_MEMORY_SCOPE_AGENT); \
        svr[1] = __hip_atomic_load(&ws[(t0_) + 4 * q + 1], __ATOMIC_RELAXED, __HIP_MEMORY_SCOPE_AGENT); \
        svr[2] = __hip_atomic_load(&ws[(t0_) + 4 * q + 2], __ATOMIC_RELAXED, __HIP_MEMORY_SCOPE_AGENT); \
        svr[3] = __hip_atomic_load(&ws[(t0_) + 4 * q + 3], __ATOMIC_RELAXED, __HIP_MEMORY_SCOPE_AGENT); \
        if (__float_as_uint(svr[0]) == 0xAAAAAAAAu) svr[0] = load_s(&ws[(t0_) + 4 * q + 0]); \
        if (__float_as_uint(svr[1]) == 0xAAAAAAAAu) svr[1] = load_s(&ws[(t0_) + 4 * q + 1]); \
        if (__float_as_uint(svr[2]) == 0xAAAAAAAAu) svr[2] = load_s(&ws[(t0_) + 4 * q + 2]); \
        if (__float_as_uint(svr[3]) == 0xAAAAAAAAu) svr[3] = load_s(&ws[(t0_) + 4 * q + 3]); \
    } while (0)

    // D row 4q+j = timestep-offset; Wih frag reloaded per commit (reg relief).
#define COMMIT(nb_)                                                            \
    do {                                                                       \
        half8 af = {(_Float16)xr0.x, (_Float16)xr0.y, (_Float16)xr0.z,         \
                    (_Float16)xr0.w, (_Float16)xr1.x, (_Float16)xr1.y,         \
                    (_Float16)xr1.z, (_Float16)xr1.w};                         \
        _Pragma("unroll")                                                      \
        for (int ct = 0; ct < 8; ++ct) {                                       \
            const int gcol = 128 * (ct >> 1) + 32 * w + 16 * (ct & 1) + m;     \
            const float* wsrc = w_ih + (size_t)gcol * CIN;                     \
            half8 wf;                                                          \
            _Pragma("unroll")                                                  \
            for (int i = 0; i < 8; ++i) wf[i] = (_Float16)(wsrc[q * 8 + i] * rih); \
            const float w32  = wsrc[32] * rih;                                 \
            const float bias = b_ih[gcol] + b_hh[gcol];                        \
            f32x4 D = MFMA16H(af, wf, zero4);                                  \
            const int hcl = 32 * w + 16 * (ct & 1) + m;                        \
            const int gg  = ct >> 1;                                           \
            _Pragma("unroll")                                                  \
            for (int j = 0; j < 4; ++j)                                        \
                gxs[nb_][4 * q + j][hcl * 4 + gg] = D[j] + fmaf(w32, svr[j], bias); \
        }                                                                      \
    } while (0)

    // One LSTM step: 8 indep 4-deep MFMA chains (h broadcast in all A-rows),
    // 1 b128 gx read, lane-parallel attn partial, 1-lane pipelined combine.
#define LSTM_STEP(t_, k_, cb_)                                                 \
    {                                                                          \
        const int t  = (t_);                                                   \
        const int hb = (t + 1) & 1;                                            \
        const _Float16* hbp = &hs[hb][0];                                      \
        half8 ah0 = *(const half8*)(hbp + 0 * 32 + q * 8);                     \
        half8 ah1 = *(const half8*)(hbp + 1 * 32 + q * 8);                     \
        half8 ah2 = *(const half8*)(hbp + 2 * 32 + q * 8);                     \
        half8 ah3 = *(const half8*)(hbp + 3 * 32 + q * 8);                     \
        f32x4 gx4 = *reinterpret_cast<const f32x4*>(&gxs[cb_][k_][hcol * 4]);  \
        if (t >= 2) P = fmaf(bcast[t & 1], hpp, P);                            \
        if (w == 0 && l == 0 && t >= 1) {                                      \
            const int pp = (t - 1) & 1;                                        \
            float logit = part[pp][0] + part[pp][1] + part[pp][2] + part[pp][3] + attb; \
            float beta = __expf(logit);                                        \
            Sreg += beta;                                                      \
            bcast[pp] = beta;                                                  \
        }                                                                      \
        f32x4 a0 = MFMA16H(ah0, BREG[0][0], zero4);                            \
        f32x4 a1 = MFMA16H(ah0, BREG[1][0], zero4);                            \
        f32x4 a2 = MFMA16H(ah0, BREG[2][0], zero4);                            \
        f32x4 a3 = MFMA16H(ah0, BREG[3][0], zero4);                            \
        f32x4 a4 = MFMA16H(ah0, BREG[4][0], zero4);                            \
        f32x4 a5 = MFMA16H(ah0, BREG[5][0], zero4);                            \
        f32x4 a6 = MFMA16H(ah0, BREG[6][0], zero4);                            \
        f32x4 a7 = MFMA16H(ah0, BREG[7][0], zero4);                            \
        a0 = MFMA16H(ah1, BREG[0][1], a0);                                     \
        a1 = MFMA16H(ah1, BREG[1][1], a1);                                     \
        a2 = MFMA16H(ah1, BREG[2][1], a2);                                     \
        a3 = MFMA16H(ah1, BREG[3][1], a3);                                     \
        a4 = MFMA16H(ah1, BREG[4][1], a4);                                     \
        a5 = MFMA16H(ah1, BREG[5][1], a5);                                     \
        a6 = MFMA16H(ah1, BREG[6][1], a6);                                     \
        a7 = MFMA16H(ah1, BREG[7][1], a7);                                     \
        a0 = MFMA16H(ah2, BREG[0][2], a0);                                     \
        a1 = MFMA16H(ah2, BREG[1][2], a1);                                     \
        a2 = MFMA16H(ah2, BREG[2][2], a2);                                     \
        a3 = MFMA16H(ah2, BREG[3][2], a3);                                     \
        a4 = MFMA16H(ah2, BREG[4][2], a4);                                     \
        a5 = MFMA16H(ah2, BREG[5][2], a5);                                     \
        a6 = MFMA16H(ah2, BREG[6][2], a6);                                     \
        a7 = MFMA16H(ah2, BREG[7][2], a7);                                     \
        a0 = MFMA16H(ah3, BREG[0][3], a0);                                     \
        a1 = MFMA16H(ah3, BREG[1][3], a1);                                     \
        a2 = MFMA16H(ah3, BREG[2][3], a2);                                     \
        a3 = MFMA16H(ah3, BREG[3][3], a3);                                     \
        a4 = MFMA16H(ah3, BREG[4][3], a4);                                     \
        a5 = MFMA16H(ah3, BREG[5][3], a5);                                     \
        a6 = MFMA16H(ah3, BREG[6][3], a6);                                     \
        a7 = MFMA16H(ah3, BREG[7][3], a7);                                     \
        {                                                                      \
            const bool qo = (q & 1);                                           \
            float g0 = (qo ? a1[0] : a0[0]) + gx4[0];                          \
            float g1 = (qo ? a3[0] : a2[0]) + gx4[1];                          \
            float g2 = (qo ? a5[0] : a4[0]) + gx4[2];                          \
            float g3 = (qo ? a7[0] : a6[0]) + gx4[3];                          \
            float ig = fsig(g0);                                               \
            float fg = fsig(g1);                                               \
            float gv = ftanh(g2);                                              \
            float og = fsig(g3);                                               \
            c_st = fmaf(fg, c_st, ig * gv);                                    \
            float hv = og * ftanh(c_st);                                       \
            hpp   = hprev;                                                     \
            hprev = hv;                                                        \
            if (q < 2) hs[t & 1][hcol] = (_Float16)hv;                         \
            float pr = (q < 2) ? awj * hv : 0.f;                               \
            float tot = wave_sum_dpp(pr);                                      \
            if (l == 63) part[t & 1][w] = tot;                                 \
        }                                                                      \
    }

    // ================= Phase E: lstm main =================
    for (int i = tid; i < 2 * HSP; i += 256) (&hs[0][0])[i] = (_Float16)0.f;

    float c_st = 0.f, P = 0.f, hprev = 0.f, hpp = 0.f;
    float Sreg = 0.f;                                    // wave 0 lane 0
    float4 xr0, xr1;
    float svr[4];

    {   // chunk-0 staging (spins on ws published by all blocks' phase A;
        // co-residency of all 512 blocks guaranteed by 70KB LDS + 256 VGPR)
        XLOAD(0);
        WSPIN(0);
        COMMIT(0);
    }
    __syncthreads();

    for (int tc = 0; tc < NCH; ++tc) {
        const int cb  = tc & 1;
        const int t0n = (tc + 1) * CH;
#pragma unroll 2
        for (int k = 0; k < CH; ++k) {
            LSTM_STEP(tc * CH + k, k, cb);
            if (tc + 1 < NCH) {
                if (k == 0) XLOAD(t0n);
                else if (k == 2) WSPIN(t0n);
                else if (k == 8) COMMIT(cb ^ 1);
            }
            BARRIER();
        }
    }

    // ---- epilogue ----
    // Loop covered P up to h_{T-3}. bcast[0] = beta_{T-2} (combined at step T-1).
    P = fmaf(bcast[0], hpp, P);
    if (w == 0 && l == 0) {
        float logit = part[1][0] + part[1][1] + part[1][2] + part[1][3] + attb;
        float beta = __expf(logit);   // beta_{T-1}
        Sreg += beta;
        bcast[1] = beta;
        SfS = Sreg;
    }
    __syncthreads();
    P = fmaf(bcast[1], hprev, P);
    {
        float Pv = P * __builtin_amdgcn_rcpf(SfS) * fcwj;
        float pr = (q < 2) ? Pv : 0.f;
        float tot = wave_sum_dpp(pr);
        if (l == 63) fcp[w] = tot;
    }
    __syncthreads();
    if (tid == 0) out[brow] = fcp[0] + fcp[1] + fcp[2] + fcp[3] + fc_b[0];
}

// ---------------------------------------------------------------------------
extern "C" void kernel_launch(void* const* d_in, const int* in_sizes, int n_in,
                              void* d_out, int out_size, void* d_ws, size_t ws_size,
                              hipStream_t stream) {
    const float* x      = (const float*)d_in[0];
    const float* w_ih   = (const float*)d_in[1];
    const float* u_ih   = (const float*)d_in[2];
    const float* w_hh   = (const float*)d_in[3];
    const float* u_hh   = (const float*)d_in[4];
    const float* b_ih   = (const float*)d_in[5];
    const float* b_hh   = (const float*)d_in[6];
    const float* attn_w = (const float*)d_in[7];
    const float* attn_b = (const float*)d_in[8];
    const float* fc_w   = (const float*)d_in[9];
    const float* u_fc   = (const float*)d_in[10];
    const float* fc_b   = (const float*)d_in[11];
    float* ws  = (float*)d_ws;
    float* out = (float*)d_out;

    critic_fused<<<BB, 256, 0, stream>>>(x, w_ih, u_ih, w_hh, u_hh, b_ih, b_hh,
                                         attn_w, attn_b, fc_w, u_fc, fc_b, ws, out);
}

// Round 8
// 518.831 us; speedup vs baseline: 3.8142x; 1.2026x over previous
//
#include <hip/hip_runtime.h>
#include <math.h>

#define TT 512
#define BB 512
#define CC 32
#define CIN 33
#define HH 128
#define EPSF 1e-12f
#define CH 16              // timesteps per gx-chunk staged in LDS
#define NCH (TT / CH)
#define RB 2               // batch rows per block
#define HSP 160            // hs row stride (halves): 320 B
#define GXP 520            // gx row stride (floats) per (k,row): 512 data + 8 pad

typedef _Float16 half8 __attribute__((ext_vector_type(8)));
typedef float f32x4 __attribute__((ext_vector_type(4)));

#define MFMA16H(a, b, c) __builtin_amdgcn_mfma_f32_16x16x32_f16(a, b, c, 0, 0, 0)
// In-loop barrier: LDS visibility only (no vmcnt drain; staging loads stay in flight).
#define BARRIER() asm volatile("s_waitcnt lgkmcnt(0)\n\ts_barrier" ::: "memory")

__device__ __forceinline__ float fsig(float x) {
    return __builtin_amdgcn_rcpf(1.f + __expf(-x));
}
__device__ __forceinline__ float ftanh(float x) {
    return 1.f - 2.f * __builtin_amdgcn_rcpf(1.f + __expf(2.f * x));
}
// full-wave (64) sum via DPP; result valid on lane 63 ONLY.
__device__ __forceinline__ float wave_sum_dpp(float x) {
    x += __int_as_float(__builtin_amdgcn_update_dpp(0, __float_as_int(x), 0x111, 0xf, 0xf, true));
    x += __int_as_float(__builtin_amdgcn_update_dpp(0, __float_as_int(x), 0x112, 0xf, 0xf, true));
    x += __int_as_float(__builtin_amdgcn_update_dpp(0, __float_as_int(x), 0x114, 0xf, 0xf, true));
    x += __int_as_float(__builtin_amdgcn_update_dpp(0, __float_as_int(x), 0x118, 0xf, 0xf, true));
    x += __int_as_float(__builtin_amdgcn_update_dpp(0, __float_as_int(x), 0x142, 0xa, 0xf, true));
    x += __int_as_float(__builtin_amdgcn_update_dpp(0, __float_as_int(x), 0x143, 0xc, 0xf, true));
    return x;
}
// sum within each 16-lane row; result valid on lanes 15/31/47/63.
__device__ __forceinline__ float row_sum_dpp(float x) {
    x += __int_as_float(__builtin_amdgcn_update_dpp(0, __float_as_int(x), 0x111, 0xf, 0xf, true));
    x += __int_as_float(__builtin_amdgcn_update_dpp(0, __float_as_int(x), 0x112, 0xf, 0xf, true));
    x += __int_as_float(__builtin_amdgcn_update_dpp(0, __float_as_int(x), 0x114, 0xf, 0xf, true));
    x += __int_as_float(__builtin_amdgcn_update_dpp(0, __float_as_int(x), 0x118, 0xf, 0xf, true));
    return x;
}
// spin-load ws[t]: ws is 0xAA-poisoned each launch (sentinel). Relaxed order is
// sufficient; AGENT scope gives cross-XCD visibility. Iteration cap -> worst
// case is a wrong value, never a hang.
__device__ __forceinline__ float load_s(const float* p) {
    float v = __hip_atomic_load(p, __ATOMIC_RELAXED, __HIP_MEMORY_SCOPE_AGENT);
    for (int it = 0; it < 100000000 && __float_as_uint(v) == 0xAAAAAAAAu; ++it)
        v = __hip_atomic_load(p, __ATOMIC_RELAXED, __HIP_MEMORY_SCOPE_AGENT);
    return v;
}

// ---------------------------------------------------------------------------
// R26: all-8-compute waves (2 compute waves per SIMD), straggler-free.
// R25 established: per-block MFMA issue is fixed (~600cy/SIMD/step), so
// blocks/CU must stay 1; the lever is the ~1000cy non-MFMA overhead of R22.
// Each wave owns 16 h-cols x 4 gates (BREG[4][4], 16 MFMA/step); the SIMD
// sibling wave's MFMA stream fills this wave's DS-wait/act/drain phases.
// Stragglers removed R22/R24-style: attention = lane-parallel row_sum_dpp
// partial in the act tail + 2-lane combine pipelined one step behind
// (R24-verified scheme); staging (x-load k=0, ws-spin k=2, commit k=8) is
// per-wave for its own columns, T14-split so HBM latency hides under steps.
// Gate extract = single [q&1] cndmask; gx = one ds_read_b128.
// ---------------------------------------------------------------------------
__global__ __attribute__((amdgpu_flat_work_group_size(512, 512), amdgpu_waves_per_eu(2, 2)))
void critic_fused(
    const float* __restrict__ x,
    const float* __restrict__ w_ih, const float* __restrict__ u_ih,
    const float* __restrict__ w_hh, const float* __restrict__ u_hh,
    const float* __restrict__ b_ih, const float* __restrict__ b_hh,
    const float* __restrict__ attn_w, const float* __restrict__ attn_b,
    const float* __restrict__ fc_w, const float* __restrict__ u_fc,
    const float* __restrict__ fc_b,
    float* __restrict__ ws,
    float* __restrict__ out)
{
    const int tid = threadIdx.x;
    const int w   = tid >> 6;          // wave 0..7
    const int l   = tid & 63;          // lane
    const int m   = l & 15;            // MFMA col index
    const int q   = l >> 4;            // quad 0..3
    const int r   = q & 1;             // this lane's batch row (q,q+2 duplicate)
    const int b0  = blockIdx.x * RB;
    const int hcol = 16 * w + m;       // this lane's h column

    // ---- LDS (~141 KB -> 1 block/CU) ----
    __shared__ float4 sSS[2][8][8];                         // std wave-partials per tt
    __shared__ float4 sQQ[2][8][8];
    __shared__ float stdp[2][8];                            // per-c4 std partials
    __shared__ float red[512];                              // sigma scratch
    __shared__ float vv[128];
    __shared__ float sigS[3];                               // sig_ih, sig_hh, sig_fc
    __shared__ __align__(16) _Float16 hs[2][RB][HSP];       // h planes
    __shared__ __align__(16) float gxs[2][CH][RB][GXP];     // gate-interleaved gates_x
    __shared__ __align__(16) float bcast[2][RB];            // beta per parity,row
    __shared__ float part[2][8][RB];                        // attn wave-partials
    __shared__ float Sf[RB];
    __shared__ float fcp[8][RB];                            // FC partials

    // ===== Phase A loads issued FIRST (HBM latency hidden by phase B) =====
    const int c4 = tid & 7;       // c = c4*4 .. c4*4+3
    const int bs = tid >> 3;      // 64 groups of 8 batch rows
    float4 xa[2][8];
#pragma unroll
    for (int tt = 0; tt < 2; ++tt) {
        const int t = 2 * blockIdx.x + tt;
#pragma unroll
        for (int i = 0; i < 8; ++i)
            xa[tt][i] = *reinterpret_cast<const float4*>(
                x + ((size_t)(bs * 8 + i) * TT + t) * CC + c4 * 4);
    }

    // ===== sigma_hh projection in the loads' shadow (L2-bound) =====
    {
        const int c = tid & 127, qq = tid >> 7;
        const float* wp = w_hh + (size_t)(qq * 128) * HH + c;
        const float* up = u_hh + qq * 128;
        float a0 = 0.f, a1 = 0.f, a2 = 0.f, a3 = 0.f;
#pragma unroll 4
        for (int g = 0; g < 128; g += 4) {
            a0 = fmaf(wp[(size_t)(g + 0) * HH], up[g + 0], a0);
            a1 = fmaf(wp[(size_t)(g + 1) * HH], up[g + 1], a1);
            a2 = fmaf(wp[(size_t)(g + 2) * HH], up[g + 2], a2);
            a3 = fmaf(wp[(size_t)(g + 3) * HH], up[g + 3], a3);
        }
        red[tid] = (a0 + a1) + (a2 + a3);
    }

    // ===== Phase A reduction (registers already landed) =====
#pragma unroll
    for (int tt = 0; tt < 2; ++tt) {
        float4 S = make_float4(0.f, 0.f, 0.f, 0.f);
        float4 Q = make_float4(0.f, 0.f, 0.f, 0.f);
#pragma unroll
        for (int i = 0; i < 8; ++i) {
            float4 v = xa[tt][i];
            S.x += v.x; S.y += v.y; S.z += v.z; S.w += v.w;
            Q.x = fmaf(v.x, v.x, Q.x); Q.y = fmaf(v.y, v.y, Q.y);
            Q.z = fmaf(v.z, v.z, Q.z); Q.w = fmaf(v.w, v.w, Q.w);
        }
#pragma unroll
        for (int off = 8; off <= 32; off <<= 1) {
            S.x += __shfl_xor(S.x, off, 64); S.y += __shfl_xor(S.y, off, 64);
            S.z += __shfl_xor(S.z, off, 64); S.w += __shfl_xor(S.w, off, 64);
            Q.x += __shfl_xor(Q.x, off, 64); Q.y += __shfl_xor(Q.y, off, 64);
            Q.z += __shfl_xor(Q.z, off, 64); Q.w += __shfl_xor(Q.w, off, 64);
        }
        if (l < 8) { sSS[tt][w][c4] = S; sQQ[tt][w][c4] = Q; }
    }
    __syncthreads();   // publishes red[] (projection) + sSS/sQQ

    // disjoint groups: tid<128 -> vv combine; tid 384..399 -> std combine
    if (tid < 128) vv[tid] = red[tid] + red[tid + 128] + red[tid + 256] + red[tid + 384];
    if (tid >= 384 && tid < 400) {
        const int tt2 = (tid - 384) >> 3, cc = (tid - 384) & 7;
        float4 St = make_float4(0.f, 0.f, 0.f, 0.f);
        float4 Qt = make_float4(0.f, 0.f, 0.f, 0.f);
#pragma unroll
        for (int i = 0; i < 8; ++i) {
            float4 a = sSS[tt2][i][cc], b4 = sQQ[tt2][i][cc];
            St.x += a.x; St.y += a.y; St.z += a.z; St.w += a.w;
            Qt.x += b4.x; Qt.y += b4.y; Qt.z += b4.z; Qt.w += b4.w;
        }
        float st = 0.f;
#pragma unroll
        for (int i = 0; i < 4; ++i) {
            float s1 = (i == 0) ? St.x : (i == 1) ? St.y : (i == 2) ? St.z : St.w;
            float q1 = (i == 0) ? Qt.x : (i == 1) ? Qt.y : (i == 2) ? Qt.z : Qt.w;
            float mean = s1 / 512.0f;
            float var  = (q1 - 512.0f * mean * mean) / 511.0f;
            st += sqrtf(fmaxf(var, 0.f));
        }
        stdp[tt2][cc] = st;
    }
    __syncthreads();
    // tid 408/409: publish ws[t]; all: square vv for norm reduction
    if (tid >= 408 && tid < 410) {
        const int tt2 = tid - 408;
        float mm = 0.f;
#pragma unroll
        for (int i = 0; i < 8; ++i) mm += stdp[tt2][i];
        __hip_atomic_store(&ws[2 * blockIdx.x + tt2], mm / 32.0f, __ATOMIC_RELAXED,
                           __HIP_MEMORY_SCOPE_AGENT);
    }
    red[tid] = (tid < 128) ? vv[tid] * vv[tid] : 0.f;
    __syncthreads();

    // ===== sigma_hh: norm + W@v =====
    {
        for (int s = 64; s >= 1; s >>= 1) { if (tid < s) red[tid] += red[tid + s]; __syncthreads(); }
        const float nv = sqrtf(red[0]);
        __syncthreads();
        if (tid < 128) vv[tid] = vv[tid] / (nv + EPSF);
        __syncthreads();
        float sq = 0.f;
        float2 vl = *reinterpret_cast<const float2*>(&vv[2 * l]);
#pragma unroll 4
        for (int gi = 0; gi < 64; ++gi) {
            const int g = w * 64 + gi;
            float2 wl = *reinterpret_cast<const float2*>(&w_hh[(size_t)g * HH + 2 * l]);
            float p  = fmaf(wl.x, vl.x, wl.y * vl.y);
            float tot = wave_sum_dpp(p);
            sq = fmaf(tot, tot, sq);
        }
        if (l == 63) red[w] = sq;
        __syncthreads();
        if (tid == 0) {
            float ns2 = 0.f;
            for (int i = 0; i < 8; ++i) ns2 += red[i];
            sigS[1] = ns2 / (sqrtf(ns2) + EPSF);
        }
        __syncthreads();
    }
    // ===== sigma_ih =====
    {
        if (l < CIN) {
            float a0 = 0.f, a1 = 0.f;
#pragma unroll 4
            for (int gi = 0; gi < 64; gi += 2) {
                const int g = w * 64 + gi;
                a0 = fmaf(w_ih[(size_t)(g + 0) * CIN + l], u_ih[g + 0], a0);
                a1 = fmaf(w_ih[(size_t)(g + 1) * CIN + l], u_ih[g + 1], a1);
            }
            red[w * 64 + l] = a0 + a1;
        }
        __syncthreads();
        if (tid < CIN) {
            float v = 0.f;
#pragma unroll
            for (int i = 0; i < 8; ++i) v += red[i * 64 + tid];
            vv[tid] = v;
        }
        __syncthreads();
        if (tid == 0) {
            float n2 = 0.f;
            for (int i = 0; i < CIN; ++i) n2 += vv[i] * vv[i];
            red[400] = sqrtf(n2);
        }
        __syncthreads();
        const float nv = red[400];
        if (tid < CIN) vv[tid] = vv[tid] / (nv + EPSF);
        __syncthreads();
        float vl = (l < CIN) ? vv[l] : 0.f;
        float sq = 0.f;
#pragma unroll 4
        for (int gi = 0; gi < 64; ++gi) {
            const int g = w * 64 + gi;
            float p = (l < CIN) ? w_ih[(size_t)g * CIN + l] * vl : 0.f;
            float tot = wave_sum_dpp(p);
            sq = fmaf(tot, tot, sq);
        }
        if (l == 63) red[w] = sq;
        __syncthreads();
        if (tid == 0) {
            float ns2 = 0.f;
            for (int i = 0; i < 8; ++i) ns2 += red[i];
            sigS[0] = ns2 / (sqrtf(ns2) + EPSF);
        }
        __syncthreads();
    }
    // ===== sigma_fc =====
    {
        red[tid] = (tid < 128) ? fc_w[tid] * fc_w[tid] : 0.f;
        __syncthreads();
        for (int s = 64; s >= 1; s >>= 1) { if (tid < s) red[tid] += red[tid + s]; __syncthreads(); }
        if (tid == 0) {
            float nw2 = red[0];
            float u0  = u_fc[0];
            float nv  = fabsf(u0) * sqrtf(nw2);
            float wv  = u0 * nw2 / (nv + EPSF);
            sigS[2]   = wv * wv / (fabsf(wv) + EPSF);
        }
        __syncthreads();
    }
    const float rih = 1.f / sigS[0];
    const float rhh = 1.f / sigS[1];
    const float rfc = 1.f / sigS[2];
    const float attb = attn_b[0];
    const float awj  = attn_w[hcol];
    const float fcwj = fc_w[hcol] * rfc;

    // ================= Phase C: Whh fragments (64 VGPR) =================
    // wave w owns h-cols 16w+m; gates g: gcol = 128g + 16w + m.
    half8 BREG[4][4];
#pragma unroll
    for (int g = 0; g < 4; ++g) {
        const int gcol = 128 * g + hcol;
#pragma unroll
        for (int kt = 0; kt < 4; ++kt) {
            const float* src = w_hh + (size_t)gcol * HH + kt * 32 + q * 8;
#pragma unroll
            for (int i = 0; i < 8; ++i) BREG[g][kt][i] = (_Float16)(src[i] * rhh);
        }
    }
    f32x4 zero4 = (f32x4){0.f, 0.f, 0.f, 0.f};
#pragma unroll
    for (int g = 0; g < 4; ++g)
#pragma unroll
        for (int kt = 0; kt < 4; ++kt) asm volatile("" : "+v"(BREG[g][kt]));
    asm volatile("" : "+v"(zero4));

    // ---- staging: A-row (0..31) = (k,rr); lane m holds rows m, m+16
    //      -> k = 8*mt+(m>>1), rr = m&1. All waves load (same A, own cols). ----
#define XLOAD(t0_)                                                             \
    do {                                                                       \
        _Pragma("unroll")                                                      \
        for (int mt = 0; mt < 2; ++mt) {                                       \
            const size_t base =                                                \
                ((size_t)(b0 + (m & 1)) * TT + ((t0_) + 8 * mt + (m >> 1))) *  \
                    CC + q * 8;                                                \
            xr[mt][0] = *reinterpret_cast<const float4*>(x + base);            \
            xr[mt][1] = *reinterpret_cast<const float4*>(x + base + 4);        \
        }                                                                      \
    } while (0)

#define WSPIN(t0_)                                                             \
    do {                                                                       \
        svr[0] = load_s(&ws[(t0_) + 2 * q]);                                   \
        svr[1] = load_s(&ws[(t0_) + 2 * q + 1]);                               \
        svr[2] = load_s(&ws[(t0_) + 8 + 2 * q]);                               \
        svr[3] = load_s(&ws[(t0_) + 8 + 2 * q + 1]);                           \
    } while (0)

    // D row (within mt) 4q+j -> k = 8mt+2q+(j>>1), rr = j&1. Lane writes
    // gate-interleaved f32x4 (bias + w32*std folded) for its 16 h-cols.
#define COMMIT(nb_)                                                            \
    do {                                                                       \
        _Pragma("unroll")                                                      \
        for (int mt = 0; mt < 2; ++mt) {                                       \
            half8 af = {(_Float16)xr[mt][0].x, (_Float16)xr[mt][0].y,          \
                        (_Float16)xr[mt][0].z, (_Float16)xr[mt][0].w,          \
                        (_Float16)xr[mt][1].x, (_Float16)xr[mt][1].y,          \
                        (_Float16)xr[mt][1].z, (_Float16)xr[mt][1].w};         \
            f32x4 sg[4]; float w32g[4], biasg[4];                              \
            _Pragma("unroll")                                                  \
            for (int g = 0; g < 4; ++g) {                                      \
                const int gcol = 128 * g + hcol;                               \
                const float* wsrc = w_ih + (size_t)gcol * CIN;                 \
                half8 wf;                                                      \
                _Pragma("unroll")                                              \
                for (int i = 0; i < 8; ++i) wf[i] = (_Float16)(wsrc[q * 8 + i] * rih); \
                sg[g] = MFMA16H(af, wf, zero4);                                \
                w32g[g]  = wsrc[32] * rih;                                     \
                biasg[g] = b_ih[gcol] + b_hh[gcol];                            \
            }                                                                  \
            _Pragma("unroll")                                                  \
            for (int j = 0; j < 4; ++j) {                                      \
                const float sv = (j & 2) ? svr[2 * mt + 1] : svr[2 * mt];      \
                f32x4 gv;                                                      \
                gv[0] = sg[0][j] + fmaf(w32g[0], sv, biasg[0]);                \
                gv[1] = sg[1][j] + fmaf(w32g[1], sv, biasg[1]);                \
                gv[2] = sg[2][j] + fmaf(w32g[2], sv, biasg[2]);                \
                gv[3] = sg[3][j] + fmaf(w32g[3], sv, biasg[3]);                \
                *reinterpret_cast<f32x4*>(                                     \
                    &gxs[nb_][8 * mt + 2 * q + (j >> 1)][j & 1][hcol * 4]) = gv; \
            }                                                                  \
        }                                                                      \
    } while (0)

    // One LSTM step: 16 MFMA (4 gate-chains, 4-deep), 1 b128 gx read,
    // [q&1]-select extract, lane-parallel attn partial (row_sum_dpp),
    // 2-lane combine one step behind (wave 7), raw barrier.
#define LSTM_STEP(t_, k_, cb_)                                                 \
    {                                                                          \
        const int t  = (t_);                                                   \
        const int hb = (t + 1) & 1;                                            \
        half8 ah0 = *(const half8*)&hs[hb][m & 1][0 * 32 + q * 8];             \
        half8 ah1 = *(const half8*)&hs[hb][m & 1][1 * 32 + q * 8];             \
        half8 ah2 = *(const half8*)&hs[hb][m & 1][2 * 32 + q * 8];             \
        half8 ah3 = *(const half8*)&hs[hb][m & 1][3 * 32 + q * 8];             \
        f32x4 gx4 = *reinterpret_cast<const f32x4*>(&gxs[cb_][k_][r][hcol * 4]); \
        if (t >= 2) P = fmaf(bcast[t & 1][r], hpp, P);                         \
        if (w == 7 && l < 2 && t >= 1) {                                       \
            const int pp = (t - 1) & 1;                                        \
            float logit = attb;                                                \
            _Pragma("unroll")                                                  \
            for (int i = 0; i < 8; ++i) logit += part[pp][i][l];               \
            float beta = __expf(logit);                                        \
            Sreg += beta;                                                      \
            bcast[pp][l] = beta;                                               \
        }                                                                      \
        f32x4 A0 = MFMA16H(ah0, BREG[0][0], zero4);                            \
        f32x4 A1 = MFMA16H(ah0, BREG[1][0], zero4);                            \
        f32x4 A2 = MFMA16H(ah0, BREG[2][0], zero4);                            \
        f32x4 A3 = MFMA16H(ah0, BREG[3][0], zero4);                            \
        A0 = MFMA16H(ah1, BREG[0][1], A0);                                     \
        A1 = MFMA16H(ah1, BREG[1][1], A1);                                     \
        A2 = MFMA16H(ah1, BREG[2][1], A2);                                     \
        A3 = MFMA16H(ah1, BREG[3][1], A3);                                     \
        A0 = MFMA16H(ah2, BREG[0][2], A0);                                     \
        A1 = MFMA16H(ah2, BREG[1][2], A1);                                     \
        A2 = MFMA16H(ah2, BREG[2][2], A2);                                     \
        A3 = MFMA16H(ah2, BREG[3][2], A3);                                     \
        A0 = MFMA16H(ah3, BREG[0][3], A0);                                     \
        A1 = MFMA16H(ah3, BREG[1][3], A1);                                     \
        A2 = MFMA16H(ah3, BREG[2][3], A2);                                     \
        A3 = MFMA16H(ah3, BREG[3][3], A3);                                     \
        {                                                                      \
            float g0 = (r ? A0[1] : A0[0]) + gx4[0];                           \
            float g1 = (r ? A1[1] : A1[0]) + gx4[1];                           \
            float g2 = (r ? A2[1] : A2[0]) + gx4[2];                           \
            float g3 = (r ? A3[1] : A3[0]) + gx4[3];                           \
            float ig = fsig(g0);                                               \
            float fg = fsig(g1);                                               \
            float gg = ftanh(g2);                                              \
            float og = fsig(g3);                                               \
            c_st = fmaf(fg, c_st, ig * gg);                                    \
            float hv = og * ftanh(c_st);                                       \
            hpp   = hprev;                                                     \
            hprev = hv;                                                        \
            if (q < 2) hs[t & 1][q][hcol] = (_Float16)hv;                      \
            float pr = (q < 2) ? awj * hv : 0.f;                               \
            float rs = row_sum_dpp(pr);                                        \
            if ((l & 15) == 15 && q < 2) part[t & 1][w][q] = rs;               \
        }                                                                      \
        BARRIER();                                                             \
    }

    // ================= Phase E: lstm main =================
    for (int i = tid; i < 2 * RB * HSP; i += 512) (&hs[0][0][0])[i] = (_Float16)0.f;

    float c_st = 0.f, P = 0.f, hprev = 0.f, hpp = 0.f;  // per-lane, row r
    float Sreg = 0.f;                                    // wave 7 lanes 0,1
    float4 xr[2][2];
    float svr[4];

    {   // chunk-0 staging (spins on ws published by all blocks' phase A)
        XLOAD(0);
        WSPIN(0);
        COMMIT(0);
    }
    __syncthreads();

    for (int tc = 0; tc < NCH; ++tc) {
        const int cb  = tc & 1;
        const int t0n = (tc + 1) * CH;
#pragma unroll 2
        for (int k = 0; k < CH; ++k) {
            LSTM_STEP(tc * CH + k, k, cb);
            if (tc + 1 < NCH) {
                if (k == 0) XLOAD(t0n);            // issue early (T14)
                else if (k == 2) WSPIN(t0n);
                else if (k == 8) COMMIT(cb ^ 1);   // commit mid-chunk
            }
        }
    }

    // ---- epilogue ----
    // Loop P covered beta_0..beta_509 x h. bcast[0] = beta_510 (combined at
    // step 511); part[1] holds h_511 partials.
    P = fmaf(bcast[0][r], hpp, P);
    if (w == 7 && l < 2) {
        float logit = attb;
#pragma unroll
        for (int i = 0; i < 8; ++i) logit += part[1][i][l];
        float beta = __expf(logit);   // beta_511
        Sreg += beta;
        bcast[1][l] = beta;
        Sf[l] = Sreg;
    }
    __syncthreads();
    P = fmaf(bcast[1][r], hprev, P);
    {
        float Pv = P * __builtin_amdgcn_rcpf(Sf[r]) * fcwj;
        float pr = (q < 2) ? Pv : 0.f;
        float rs = row_sum_dpp(pr);
        if ((l & 15) == 15 && q < 2) fcp[w][q] = rs;
    }
    __syncthreads();
    if (tid < RB) {
        float a = 0.f;
#pragma unroll
        for (int i = 0; i < 8; ++i) a += fcp[i][tid];
        out[b0 + tid] = a + fc_b[0];
    }
}

// ---------------------------------------------------------------------------
extern "C" void kernel_launch(void* const* d_in, const int* in_sizes, int n_in,
                              void* d_out, int out_size, void* d_ws, size_t ws_size,
                              hipStream_t stream) {
    const float* x      = (const float*)d_in[0];
    const float* w_ih   = (const float*)d_in[1];
    const float* u_ih   = (const float*)d_in[2];
    const float* w_hh   = (const float*)d_in[3];
    const float* u_hh   = (const float*)d_in[4];
    const float* b_ih   = (const float*)d_in[5];
    const float* b_hh   = (const float*)d_in[6];
    const float* attn_w = (const float*)d_in[7];
    const float* attn_b = (const float*)d_in[8];
    const float* fc_w   = (const float*)d_in[9];
    const float* u_fc   = (const float*)d_in[10];
    const float* fc_b   = (const float*)d_in[11];
    float* ws  = (float*)d_ws;
    float* out = (float*)d_out;

    critic_fused<<<BB / RB, 512, 0, stream>>>(x, w_ih, u_ih, w_hh, u_hh, b_ih, b_hh,
                                              attn_w, attn_b, fc_w, u_fc, fc_b, ws, out);
}

// Round 9
// 400.787 us; speedup vs baseline: 4.9376x; 1.2945x over previous
//
#include <hip/hip_runtime.h>
#include <math.h>

#define TT 512
#define BB 512
#define CC 32
#define CIN 33
#define HH 128
#define EPSF 1e-12f
#define CH 16              // timesteps per gx-chunk staged in LDS
#define NCH (TT / CH)
#define RB 2               // batch rows per block
#define HSP 160            // hs row stride (halves): 320 B
#define GXP 520            // gx row stride (floats) per (k,row): 512 data + 8 pad

typedef _Float16 half8 __attribute__((ext_vector_type(8)));
typedef _Float16 half2v __attribute__((ext_vector_type(2)));
typedef float f32x4 __attribute__((ext_vector_type(4)));

#define MFMA16H(a, b, c) __builtin_amdgcn_mfma_f32_16x16x32_f16(a, b, c, 0, 0, 0)
// In-loop barrier: LDS visibility only (no vmcnt drain; staging loads stay in flight).
#define BARRIER() asm volatile("s_waitcnt lgkmcnt(0)\n\ts_barrier" ::: "memory")

__device__ __forceinline__ float fsig(float x) {
    return __builtin_amdgcn_rcpf(1.f + __expf(-x));
}
__device__ __forceinline__ float ftanh(float x) {
    return 1.f - 2.f * __builtin_amdgcn_rcpf(1.f + __expf(2.f * x));
}
// full-wave (64) sum via DPP; result valid on lane 63 ONLY.
__device__ __forceinline__ float wave_sum_dpp(float x) {
    x += __int_as_float(__builtin_amdgcn_update_dpp(0, __float_as_int(x), 0x111, 0xf, 0xf, true));
    x += __int_as_float(__builtin_amdgcn_update_dpp(0, __float_as_int(x), 0x112, 0xf, 0xf, true));
    x += __int_as_float(__builtin_amdgcn_update_dpp(0, __float_as_int(x), 0x114, 0xf, 0xf, true));
    x += __int_as_float(__builtin_amdgcn_update_dpp(0, __float_as_int(x), 0x118, 0xf, 0xf, true));
    x += __int_as_float(__builtin_amdgcn_update_dpp(0, __float_as_int(x), 0x142, 0xa, 0xf, true));
    x += __int_as_float(__builtin_amdgcn_update_dpp(0, __float_as_int(x), 0x143, 0xc, 0xf, true));
    return x;
}
// sum within each 16-lane row; result valid on lanes 15/31/47/63.
__device__ __forceinline__ float row_sum_dpp(float x) {
    x += __int_as_float(__builtin_amdgcn_update_dpp(0, __float_as_int(x), 0x111, 0xf, 0xf, true));
    x += __int_as_float(__builtin_amdgcn_update_dpp(0, __float_as_int(x), 0x112, 0xf, 0xf, true));
    x += __int_as_float(__builtin_amdgcn_update_dpp(0, __float_as_int(x), 0x114, 0xf, 0xf, true));
    x += __int_as_float(__builtin_amdgcn_update_dpp(0, __float_as_int(x), 0x118, 0xf, 0xf, true));
    return x;
}
// spin-load ws[t]: ws is 0xAA-poisoned each launch (sentinel). Relaxed order is
// sufficient; AGENT scope gives cross-XCD visibility. Iteration cap -> worst
// case is a wrong value, never a hang.
__device__ __forceinline__ float load_s(const float* p) {
    float v = __hip_atomic_load(p, __ATOMIC_RELAXED, __HIP_MEMORY_SCOPE_AGENT);
    for (int it = 0; it < 100000000 && __float_as_uint(v) == 0xAAAAAAAAu; ++it)
        v = __hip_atomic_load(p, __ATOMIC_RELAXED, __HIP_MEMORY_SCOPE_AGENT);
    return v;
}

// ---------------------------------------------------------------------------
// R27: R22 (verified 338us champion: 4 compute waves x 32 MFMA + 4 service
// waves owning logits/staging, weights register-cached) + two micro-levers:
// (1) s_setprio(1) around the compute MFMA cluster -- T5 requires wave role
// diversity, which this shape has; keeps the matrix pipe fed while service
// waves burst logit/staging issue on the shared SIMD. (2) gx prefetch one
// step ahead: the gx ds_read_b128 depends only on the chunk buffer, so issue
// step k+1's read mid-step (DS pipe idle under MFMA issue), removing it from
// the post-barrier critical burst. Chunk-boundary prefetch targets the buffer
// committed at k=8 (barrier-ordered); final-step prefetch is dead.
// R25/R26 established: per-SIMD MFMA issue (~620cy/step) is layout-invariant
// and this 4C+4S shape empirically beats all-compute and co-residency shapes.
// ---------------------------------------------------------------------------
__global__ __attribute__((amdgpu_flat_work_group_size(512, 512), amdgpu_waves_per_eu(2, 2)))
void critic_fused(
    const float* __restrict__ x,
    const float* __restrict__ w_ih, const float* __restrict__ u_ih,
    const float* __restrict__ w_hh, const float* __restrict__ u_hh,
    const float* __restrict__ b_ih, const float* __restrict__ b_hh,
    const float* __restrict__ attn_w, const float* __restrict__ attn_b,
    const float* __restrict__ fc_w, const float* __restrict__ u_fc,
    const float* __restrict__ fc_b,
    float* __restrict__ ws,
    float* __restrict__ out)
{
    const int tid = threadIdx.x;
    const int w   = tid >> 6;          // wave 0..7
    const int l   = tid & 63;          // lane
    const int m   = l & 15;            // A-row / B-col index
    const int q   = l >> 4;            // quad 0..3
    const int b0  = blockIdx.x * RB;
    const int sw  = w - 4;             // service wave id (valid for w>=4)
    const int col = 32 * (w & 3) + (l & 31);  // compute lane's h column
    const int row = l >> 5;            // compute lane's batch row
    const int sub = (l >> 4) & 1;      // compute lane's col-subtile

    // ---- LDS (~141 KB -> 1 block/CU) ----
    __shared__ float4 sSS[2][8][8];                         // std wave-partials per tt
    __shared__ float4 sQQ[2][8][8];
    __shared__ float stdp[2][8];                            // per-c4 std partials
    __shared__ float red[512];                              // sigma scratch
    __shared__ float vv[128];
    __shared__ float sigS[3];                               // sig_ih, sig_hh, sig_fc
    __shared__ __align__(16) _Float16 hs[2][RB][HSP];       // h planes
    __shared__ __align__(16) float gxs[2][CH][RB][GXP];     // gate-interleaved gates_x
    __shared__ __align__(8) float bcast[2][RB];             // beta per row
    __shared__ float Sf[RB];
    __shared__ float part[4][4];                            // FC partials

    // ===== Phase A loads issued FIRST (HBM latency hidden by phase B) =====
    const int c4 = tid & 7;       // c = c4*4 .. c4*4+3
    const int bs = tid >> 3;      // 64 groups of 8 batch rows
    float4 xa[2][8];
#pragma unroll
    for (int tt = 0; tt < 2; ++tt) {
        const int t = 2 * blockIdx.x + tt;
#pragma unroll
        for (int i = 0; i < 8; ++i)
            xa[tt][i] = *reinterpret_cast<const float4*>(
                x + ((size_t)(bs * 8 + i) * TT + t) * CC + c4 * 4);
    }

    // ===== sigma_hh projection in the loads' shadow (L2-bound) =====
    {
        const int c = tid & 127, qq = tid >> 7;
        const float* wp = w_hh + (size_t)(qq * 128) * HH + c;
        const float* up = u_hh + qq * 128;
        float a0 = 0.f, a1 = 0.f, a2 = 0.f, a3 = 0.f;
#pragma unroll 4
        for (int g = 0; g < 128; g += 4) {
            a0 = fmaf(wp[(size_t)(g + 0) * HH], up[g + 0], a0);
            a1 = fmaf(wp[(size_t)(g + 1) * HH], up[g + 1], a1);
            a2 = fmaf(wp[(size_t)(g + 2) * HH], up[g + 2], a2);
            a3 = fmaf(wp[(size_t)(g + 3) * HH], up[g + 3], a3);
        }
        red[tid] = (a0 + a1) + (a2 + a3);
    }

    // ===== Phase A reduction (registers already landed) =====
#pragma unroll
    for (int tt = 0; tt < 2; ++tt) {
        float4 S = make_float4(0.f, 0.f, 0.f, 0.f);
        float4 Q = make_float4(0.f, 0.f, 0.f, 0.f);
#pragma unroll
        for (int i = 0; i < 8; ++i) {
            float4 v = xa[tt][i];
            S.x += v.x; S.y += v.y; S.z += v.z; S.w += v.w;
            Q.x = fmaf(v.x, v.x, Q.x); Q.y = fmaf(v.y, v.y, Q.y);
            Q.z = fmaf(v.z, v.z, Q.z); Q.w = fmaf(v.w, v.w, Q.w);
        }
#pragma unroll
        for (int off = 8; off <= 32; off <<= 1) {
            S.x += __shfl_xor(S.x, off, 64); S.y += __shfl_xor(S.y, off, 64);
            S.z += __shfl_xor(S.z, off, 64); S.w += __shfl_xor(S.w, off, 64);
            Q.x += __shfl_xor(Q.x, off, 64); Q.y += __shfl_xor(Q.y, off, 64);
            Q.z += __shfl_xor(Q.z, off, 64); Q.w += __shfl_xor(Q.w, off, 64);
        }
        if (l < 8) { sSS[tt][w][c4] = S; sQQ[tt][w][c4] = Q; }
    }
    __syncthreads();   // publishes red[] (projection) + sSS/sQQ

    // disjoint groups: tid<128 -> vv combine; tid 384..399 -> std combine
    if (tid < 128) vv[tid] = red[tid] + red[tid + 128] + red[tid + 256] + red[tid + 384];
    if (tid >= 384 && tid < 400) {
        const int tt2 = (tid - 384) >> 3, cc = (tid - 384) & 7;
        float4 St = make_float4(0.f, 0.f, 0.f, 0.f);
        float4 Qt = make_float4(0.f, 0.f, 0.f, 0.f);
#pragma unroll
        for (int i = 0; i < 8; ++i) {
            float4 a = sSS[tt2][i][cc], b4 = sQQ[tt2][i][cc];
            St.x += a.x; St.y += a.y; St.z += a.z; St.w += a.w;
            Qt.x += b4.x; Qt.y += b4.y; Qt.z += b4.z; Qt.w += b4.w;
        }
        float st = 0.f;
#pragma unroll
        for (int i = 0; i < 4; ++i) {
            float s1 = (i == 0) ? St.x : (i == 1) ? St.y : (i == 2) ? St.z : St.w;
            float q1 = (i == 0) ? Qt.x : (i == 1) ? Qt.y : (i == 2) ? Qt.z : Qt.w;
            float mean = s1 / 512.0f;
            float var  = (q1 - 512.0f * mean * mean) / 511.0f;
            st += sqrtf(fmaxf(var, 0.f));
        }
        stdp[tt2][cc] = st;
    }
    __syncthreads();
    // tid 408/409: publish ws[t]; all: square vv for norm reduction
    if (tid >= 408 && tid < 410) {
        const int tt2 = tid - 408;
        float mm = 0.f;
#pragma unroll
        for (int i = 0; i < 8; ++i) mm += stdp[tt2][i];
        __hip_atomic_store(&ws[2 * blockIdx.x + tt2], mm / 32.0f, __ATOMIC_RELAXED,
                           __HIP_MEMORY_SCOPE_AGENT);
    }
    red[tid] = (tid < 128) ? vv[tid] * vv[tid] : 0.f;
    __syncthreads();

    // ===== sigma_hh: norm + W@v =====
    {
        for (int s = 64; s >= 1; s >>= 1) { if (tid < s) red[tid] += red[tid + s]; __syncthreads(); }
        const float nv = sqrtf(red[0]);
        __syncthreads();
        if (tid < 128) vv[tid] = vv[tid] / (nv + EPSF);
        __syncthreads();
        float sq = 0.f;
        float2 vl = *reinterpret_cast<const float2*>(&vv[2 * l]);
#pragma unroll 4
        for (int gi = 0; gi < 64; ++gi) {
            const int g = w * 64 + gi;
            float2 wl = *reinterpret_cast<const float2*>(&w_hh[(size_t)g * HH + 2 * l]);
            float p  = fmaf(wl.x, vl.x, wl.y * vl.y);
            float tot = wave_sum_dpp(p);
            sq = fmaf(tot, tot, sq);
        }
        if (l == 63) red[w] = sq;
        __syncthreads();
        if (tid == 0) {
            float ns2 = 0.f;
            for (int i = 0; i < 8; ++i) ns2 += red[i];
            sigS[1] = ns2 / (sqrtf(ns2) + EPSF);
        }
        __syncthreads();
    }
    // ===== sigma_ih =====
    {
        if (l < CIN) {
            float a0 = 0.f, a1 = 0.f;
#pragma unroll 4
            for (int gi = 0; gi < 64; gi += 2) {
                const int g = w * 64 + gi;
                a0 = fmaf(w_ih[(size_t)(g + 0) * CIN + l], u_ih[g + 0], a0);
                a1 = fmaf(w_ih[(size_t)(g + 1) * CIN + l], u_ih[g + 1], a1);
            }
            red[w * 64 + l] = a0 + a1;
        }
        __syncthreads();
        if (tid < CIN) {
            float v = 0.f;
#pragma unroll
            for (int i = 0; i < 8; ++i) v += red[i * 64 + tid];
            vv[tid] = v;
        }
        __syncthreads();
        if (tid == 0) {
            float n2 = 0.f;
            for (int i = 0; i < CIN; ++i) n2 += vv[i] * vv[i];
            red[400] = sqrtf(n2);
        }
        __syncthreads();
        const float nv = red[400];
        if (tid < CIN) vv[tid] = vv[tid] / (nv + EPSF);
        __syncthreads();
        float vl = (l < CIN) ? vv[l] : 0.f;
        float sq = 0.f;
#pragma unroll 4
        for (int gi = 0; gi < 64; ++gi) {
            const int g = w * 64 + gi;
            float p = (l < CIN) ? w_ih[(size_t)g * CIN + l] * vl : 0.f;
            float tot = wave_sum_dpp(p);
            sq = fmaf(tot, tot, sq);
        }
        if (l == 63) red[w] = sq;
        __syncthreads();
        if (tid == 0) {
            float ns2 = 0.f;
            for (int i = 0; i < 8; ++i) ns2 += red[i];
            sigS[0] = ns2 / (sqrtf(ns2) + EPSF);
        }
        __syncthreads();
    }
    // ===== sigma_fc =====
    {
        red[tid] = (tid < 128) ? fc_w[tid] * fc_w[tid] : 0.f;
        __syncthreads();
        for (int s = 64; s >= 1; s >>= 1) { if (tid < s) red[tid] += red[tid + s]; __syncthreads(); }
        if (tid == 0) {
            float nw2 = red[0];
            float u0  = u_fc[0];
            float nv  = fabsf(u0) * sqrtf(nw2);
            float wv  = u0 * nw2 / (nv + EPSF);
            sigS[2]   = wv * wv / (fabsf(wv) + EPSF);
        }
        __syncthreads();
    }
    const float rih = 1.f / sigS[0];
    const float rhh = 1.f / sigS[1];
    const float rfc = 1.f / sigS[2];
    const float attb = attn_b[0];

    // ================= Phase C: role-split weight conversion =================
    // compute (w<4): BREG[p][sub][kt] = Whh B-frags for cols 32w+16sub+m.
    // service (w>=4): BREG[p][sub][0] aliased as Wih B-frags for its cols.
    half8 BREG[4][2][4];
    float biasg[4][2], w32g[4][2];
    float fcwj = 0.f, aw0 = 0.f, aw1 = 0.f;
    f32x4 zero4 = (f32x4){0.f, 0.f, 0.f, 0.f};
    if (w < 4) {
#pragma unroll
        for (int p = 0; p < 4; ++p)
#pragma unroll
            for (int s = 0; s < 2; ++s) {
                const int g = 128 * p + 32 * w + 16 * s + m;
#pragma unroll
                for (int kt = 0; kt < 4; ++kt) {
                    const float* src = w_hh + (size_t)g * HH + kt * 32 + q * 8;
#pragma unroll
                    for (int i = 0; i < 8; ++i) BREG[p][s][kt][i] = (_Float16)(src[i] * rhh);
                }
            }
#pragma unroll
        for (int p = 0; p < 4; ++p)
#pragma unroll
            for (int s = 0; s < 2; ++s)
#pragma unroll
                for (int kt = 0; kt < 4; ++kt) asm volatile("" : "+v"(BREG[p][s][kt]));
        fcwj = fc_w[col] * rfc;
    } else {
#pragma unroll
        for (int p = 0; p < 4; ++p)
#pragma unroll
            for (int s = 0; s < 2; ++s) {
                const int g = 128 * p + 32 * sw + 16 * s + m;
                const float* src = w_ih + (size_t)g * CIN + q * 8;
#pragma unroll
                for (int i = 0; i < 8; ++i) BREG[p][s][0][i] = (_Float16)(src[i] * rih);
                w32g[p][s]  = w_ih[(size_t)g * CIN + 32] * rih;
                biasg[p][s] = b_ih[g] + b_hh[g];
                asm volatile("" : "+v"(BREG[p][s][0]));
                asm volatile("" : "+v"(biasg[p][s]), "+v"(w32g[p][s]));
            }
        aw0 = attn_w[2 * l];
        aw1 = attn_w[2 * l + 1];
    }
    asm volatile("" : "+v"(zero4));

    // ---- staging: A-row (0..31) = (k,rr) pair; lane m holds rows m, m+16
    //      -> k = 8*mt+(m>>1), rr = m&1. ----
#define STAGE_LOAD(t0_, xr_)                                                   \
    do {                                                                       \
        _Pragma("unroll")                                                      \
        for (int mt = 0; mt < 2; ++mt) {                                       \
            const size_t base =                                                \
                ((size_t)(b0 + (m & 1)) * TT + ((t0_) + 8 * mt + (m >> 1))) *  \
                    CC + q * 8;                                                \
            xr_[mt][0] = *reinterpret_cast<const float4*>(x + base);           \
            xr_[mt][1] = *reinterpret_cast<const float4*>(x + base + 4);       \
        }                                                                      \
    } while (0)

#define STAGE_SPIN(t0_, svr_)                                                  \
    do {                                                                       \
        svr_[0] = load_s(&ws[(t0_) + 2 * q]);                                  \
        svr_[1] = load_s(&ws[(t0_) + 2 * q + 1]);                              \
        svr_[2] = load_s(&ws[(t0_) + 8 + 2 * q]);                              \
        svr_[3] = load_s(&ws[(t0_) + 8 + 2 * q + 1]);                          \
    } while (0)

    // D row (within mt) 4q+j -> k = 8mt+2q+(j>>1), rr = j&1. Lane writes
    // gate-interleaved f32x4 (bias + w32*std folded) for its service cols.
#define STAGE_COMMIT(nb_, xr_, svr_)                                           \
    do {                                                                       \
        _Pragma("unroll")                                                      \
        for (int mt = 0; mt < 2; ++mt) {                                       \
            half8 af = {(_Float16)xr_[mt][0].x, (_Float16)xr_[mt][0].y,        \
                        (_Float16)xr_[mt][0].z, (_Float16)xr_[mt][0].w,        \
                        (_Float16)xr_[mt][1].x, (_Float16)xr_[mt][1].y,        \
                        (_Float16)xr_[mt][1].z, (_Float16)xr_[mt][1].w};       \
            _Pragma("unroll")                                                  \
            for (int s = 0; s < 2; ++s) {                                      \
                f32x4 s0 = MFMA16H(af, BREG[0][s][0], zero4);                  \
                f32x4 s1 = MFMA16H(af, BREG[1][s][0], zero4);                  \
                f32x4 s2 = MFMA16H(af, BREG[2][s][0], zero4);                  \
                f32x4 s3 = MFMA16H(af, BREG[3][s][0], zero4);                  \
                _Pragma("unroll")                                              \
                for (int j = 0; j < 4; ++j) {                                  \
                    const float sv = (j & 2) ? svr_[2 * mt + 1] : svr_[2 * mt];\
                    f32x4 gv;                                                  \
                    gv[0] = s0[j] + fmaf(w32g[0][s], sv, biasg[0][s]);         \
                    gv[1] = s1[j] + fmaf(w32g[1][s], sv, biasg[1][s]);         \
                    gv[2] = s2[j] + fmaf(w32g[2][s], sv, biasg[2][s]);         \
                    gv[3] = s3[j] + fmaf(w32g[3][s], sv, biasg[3][s]);         \
                    *reinterpret_cast<f32x4*>(                                 \
                        &gxs[nb_][8 * mt + 2 * q + (j >> 1)][j & 1]            \
                            [(32 * sw + 16 * s + m) * 4]) = gv;                \
                }                                                              \
            }                                                                  \
        }                                                                      \
    } while (0)

    // ================= Phase E: lstm main =================
    for (int i = tid; i < 2 * RB * HSP; i += 512) (&hs[0][0][0])[i] = (_Float16)0.f;

    float c_st = 0.f, P = 0.f, hprev = 0.f, hpp = 0.f;  // compute lanes
    float Sreg = 0.f;                                    // service 4,5 lane 63
    float4 xr[2][2];
    float svr[4];
    f32x4 gxc;                                           // prefetched gates_x

    if (w >= 4) {   // chunk-0 staging (spins on ws published by all blocks)
        STAGE_LOAD(0, xr);
        STAGE_SPIN(0, svr);
        STAGE_COMMIT(0, xr, svr);
    }
    __syncthreads();
    if (w < 4)      // prime the gx pipeline for (tc=0, k=0)
        gxc = *reinterpret_cast<const f32x4*>(&gxs[0][0][row][col * 4]);

    for (int tc = 0; tc < NCH; ++tc) {
        const int cb  = tc & 1;
        const int t0n = (tc + 1) * CH;
#pragma unroll 2
        for (int k = 0; k < CH; ++k) {
            const int t  = tc * CH + k;
            const int hb = (t + 1) & 1;
            if (w < 4) {
                // ---------------- compute step ----------------
                half8 ah0 = *(const half8*)&hs[hb][m & 1][0 * 32 + q * 8];
                half8 ah1 = *(const half8*)&hs[hb][m & 1][1 * 32 + q * 8];
                half8 ah2 = *(const half8*)&hs[hb][m & 1][2 * 32 + q * 8];
                half8 ah3 = *(const half8*)&hs[hb][m & 1][3 * 32 + q * 8];
                if (t >= 2) P = fmaf(bcast[(t - 1) & 1][row], hpp, P);
                __builtin_amdgcn_s_setprio(1);
                f32x4 c00 = MFMA16H(ah0, BREG[0][0][0], zero4);
                f32x4 c10 = MFMA16H(ah0, BREG[0][1][0], zero4);
                f32x4 c01 = MFMA16H(ah0, BREG[1][0][0], zero4);
                f32x4 c11 = MFMA16H(ah0, BREG[1][1][0], zero4);
                f32x4 c02 = MFMA16H(ah0, BREG[2][0][0], zero4);
                f32x4 c12 = MFMA16H(ah0, BREG[2][1][0], zero4);
                f32x4 c03 = MFMA16H(ah0, BREG[3][0][0], zero4);
                f32x4 c13 = MFMA16H(ah0, BREG[3][1][0], zero4);
                c00 = MFMA16H(ah1, BREG[0][0][1], c00);
                c10 = MFMA16H(ah1, BREG[0][1][1], c10);
                c01 = MFMA16H(ah1, BREG[1][0][1], c01);
                c11 = MFMA16H(ah1, BREG[1][1][1], c11);
                c02 = MFMA16H(ah1, BREG[2][0][1], c02);
                c12 = MFMA16H(ah1, BREG[2][1][1], c12);
                c03 = MFMA16H(ah1, BREG[3][0][1], c03);
                c13 = MFMA16H(ah1, BREG[3][1][1], c13);
                c00 = MFMA16H(ah2, BREG[0][0][2], c00);
                c10 = MFMA16H(ah2, BREG[0][1][2], c10);
                c01 = MFMA16H(ah2, BREG[1][0][2], c01);
                c11 = MFMA16H(ah2, BREG[1][1][2], c11);
                c02 = MFMA16H(ah2, BREG[2][0][2], c02);
                c12 = MFMA16H(ah2, BREG[2][1][2], c12);
                c03 = MFMA16H(ah2, BREG[3][0][2], c03);
                c13 = MFMA16H(ah2, BREG[3][1][2], c13);
                c00 = MFMA16H(ah3, BREG[0][0][3], c00);
                c10 = MFMA16H(ah3, BREG[0][1][3], c10);
                c01 = MFMA16H(ah3, BREG[1][0][3], c01);
                c11 = MFMA16H(ah3, BREG[1][1][3], c11);
                c02 = MFMA16H(ah3, BREG[2][0][3], c02);
                c12 = MFMA16H(ah3, BREG[2][1][3], c12);
                c03 = MFMA16H(ah3, BREG[3][0][3], c03);
                c13 = MFMA16H(ah3, BREG[3][1][3], c13);
                __builtin_amdgcn_s_setprio(0);
                // prefetch next step's gx while MFMAs drain (DS pipe idle)
                const int kn  = (k + 1) & (CH - 1);
                const int cbn = (k == CH - 1) ? (cb ^ 1) : cb;
                f32x4 gxn = *reinterpret_cast<const f32x4*>(&gxs[cbn][kn][row][col * 4]);
                // D reg j holds batch row j&1; select reg by row, acc by sub.
                float g0 = (sub ? (row ? c10[1] : c10[0]) : (row ? c00[1] : c00[0])) + gxc[0];
                float g1 = (sub ? (row ? c11[1] : c11[0]) : (row ? c01[1] : c01[0])) + gxc[1];
                float g2 = (sub ? (row ? c12[1] : c12[0]) : (row ? c02[1] : c02[0])) + gxc[2];
                float g3 = (sub ? (row ? c13[1] : c13[0]) : (row ? c03[1] : c03[0])) + gxc[3];
                float ig = fsig(g0);
                float fg = fsig(g1);
                float gg = ftanh(g2);
                float og = fsig(g3);
                c_st = fmaf(fg, c_st, ig * gg);
                float hv = og * ftanh(c_st);
                hpp   = hprev;
                hprev = hv;
                hs[t & 1][row][col] = (_Float16)hv;
                gxc = gxn;
            } else {
                // ---------------- service step ----------------
                if (sw < 2 && t > 0) {
                    half2v hh = *(const half2v*)&hs[hb][sw][2 * l];
                    float dotp = fmaf(aw0, (float)hh[0], aw1 * (float)hh[1]);
                    float tot = wave_sum_dpp(dotp);
                    if (l == 63) {
                        float beta = __expf(tot + attb);
                        Sreg += beta;
                        bcast[t & 1][sw] = beta;
                    }
                }
                if (tc + 1 < NCH) {
                    if (k == 0) STAGE_LOAD(t0n, xr);
                    else if (k == 4) STAGE_SPIN(t0n, svr);
                    else if (k == 8) STAGE_COMMIT(cb ^ 1, xr, svr);
                }
            }
            BARRIER();
        }
    }

    // ---- epilogue ----
    if (w < 4) P = fmaf(bcast[1][row], hpp, P);
    if (w >= 4 && sw < 2) {
        half2v hh = *(const half2v*)&hs[1][sw][2 * l];
        float dotp = fmaf(aw0, (float)hh[0], aw1 * (float)hh[1]);
        float tot = wave_sum_dpp(dotp);
        if (l == 63) {
            float beta = __expf(tot + attb);
            Sreg += beta;
            bcast[0][sw] = beta;
            Sf[sw] = Sreg;
        }
    }
    __syncthreads();
    if (w < 4) {
        float Pv = fmaf(bcast[0][row], hprev, P);
        float v  = Pv * __builtin_amdgcn_rcpf(Sf[row]) * fcwj;
        float rs = row_sum_dpp(v);
        if ((l & 15) == 15) part[w][q] = rs;   // q: 0,1 -> row0 subtiles; 2,3 -> row1
    }
    __syncthreads();
    if (tid < RB) {
        float a = 0.f;
#pragma unroll
        for (int i = 0; i < 4; ++i) a += part[i][2 * tid] + part[i][2 * tid + 1];
        out[b0 + tid] = a + fc_b[0];
    }
}

// ---------------------------------------------------------------------------
extern "C" void kernel_launch(void* const* d_in, const int* in_sizes, int n_in,
                              void* d_out, int out_size, void* d_ws, size_t ws_size,
                              hipStream_t stream) {
    const float* x      = (const float*)d_in[0];
    const float* w_ih   = (const float*)d_in[1];
    const float* u_ih   = (const float*)d_in[2];
    const float* w_hh   = (const float*)d_in[3];
    const float* u_hh   = (const float*)d_in[4];
    const float* b_ih   = (const float*)d_in[5];
    const float* b_hh   = (const float*)d_in[6];
    const float* attn_w = (const float*)d_in[7];
    const float* attn_b = (const float*)d_in[8];
    const float* fc_w   = (const float*)d_in[9];
    const float* u_fc   = (const float*)d_in[10];
    const float* fc_b   = (const float*)d_in[11];
    float* ws  = (float*)d_ws;
    float* out = (float*)d_out;

    critic_fused<<<BB / RB, 512, 0, stream>>>(x, w_ih, u_ih, w_hh, u_hh, b_ih, b_hh,
                                              attn_w, attn_b, fc_w, u_fc, fc_b, ws, out);
}

// Round 10
// 394.031 us; speedup vs baseline: 5.0223x; 1.0171x over previous
//
#include <hip/hip_runtime.h>
#include <math.h>

#define TT 512
#define BB 512
#define CC 32
#define CIN 33
#define HH 128
#define EPSF 1e-12f
#define CH 16              // timesteps per gx-chunk staged in LDS
#define NCH (TT / CH)
#define RB 2               // batch rows per block
#define HSP 160            // hs row stride (halves): 320 B
#define GXP 520            // gx row stride (floats) per (k,row): 512 data + 8 pad

typedef _Float16 half8 __attribute__((ext_vector_type(8)));
typedef _Float16 half2v __attribute__((ext_vector_type(2)));
typedef float f32x4 __attribute__((ext_vector_type(4)));

#define MFMA16H(a, b, c) __builtin_amdgcn_mfma_f32_16x16x32_f16(a, b, c, 0, 0, 0)
// In-loop barrier: LDS visibility only (no vmcnt drain; staging loads stay in flight).
#define BARRIER() asm volatile("s_waitcnt lgkmcnt(0)\n\ts_barrier" ::: "memory")

__device__ __forceinline__ float fsig(float x) {
    return __builtin_amdgcn_rcpf(1.f + __expf(-x));
}
__device__ __forceinline__ float ftanh(float x) {
    return 1.f - 2.f * __builtin_amdgcn_rcpf(1.f + __expf(2.f * x));
}
// full-wave (64) sum via DPP; result valid on lane 63 ONLY.
__device__ __forceinline__ float wave_sum_dpp(float x) {
    x += __int_as_float(__builtin_amdgcn_update_dpp(0, __float_as_int(x), 0x111, 0xf, 0xf, true));
    x += __int_as_float(__builtin_amdgcn_update_dpp(0, __float_as_int(x), 0x112, 0xf, 0xf, true));
    x += __int_as_float(__builtin_amdgcn_update_dpp(0, __float_as_int(x), 0x114, 0xf, 0xf, true));
    x += __int_as_float(__builtin_amdgcn_update_dpp(0, __float_as_int(x), 0x118, 0xf, 0xf, true));
    x += __int_as_float(__builtin_amdgcn_update_dpp(0, __float_as_int(x), 0x142, 0xa, 0xf, true));
    x += __int_as_float(__builtin_amdgcn_update_dpp(0, __float_as_int(x), 0x143, 0xc, 0xf, true));
    return x;
}
// sum within each 16-lane row; result valid on lanes 15/31/47/63.
__device__ __forceinline__ float row_sum_dpp(float x) {
    x += __int_as_float(__builtin_amdgcn_update_dpp(0, __float_as_int(x), 0x111, 0xf, 0xf, true));
    x += __int_as_float(__builtin_amdgcn_update_dpp(0, __float_as_int(x), 0x112, 0xf, 0xf, true));
    x += __int_as_float(__builtin_amdgcn_update_dpp(0, __float_as_int(x), 0x114, 0xf, 0xf, true));
    x += __int_as_float(__builtin_amdgcn_update_dpp(0, __float_as_int(x), 0x118, 0xf, 0xf, true));
    return x;
}
// spin-load ws[t]: ws is 0xAA-poisoned each launch (sentinel). Relaxed order is
// sufficient; AGENT scope gives cross-XCD visibility. Iteration cap -> worst
// case is a wrong value, never a hang.
__device__ __forceinline__ float load_s(const float* p) {
    float v = __hip_atomic_load(p, __ATOMIC_RELAXED, __HIP_MEMORY_SCOPE_AGENT);
    for (int it = 0; it < 100000000 && __float_as_uint(v) == 0xAAAAAAAAu; ++it)
        v = __hip_atomic_load(p, __ATOMIC_RELAXED, __HIP_MEMORY_SCOPE_AGENT);
    return v;
}

// ---------------------------------------------------------------------------
// R28 = R22 verbatim (the verified 338us champion). Search record: R19
// (-MFMA: null), R20/R23 (co-residency: VGPR spill death), R21 (de-fuse:
// -24%), R24/R25 (256-thr co-residency: -83%), R26 (8-compute: -42%), R27
// (setprio+prefetch: -4% -- setprio delays the service barrier-tail wave).
// Structure: waves 0-3 = compute (32 gate-cols each, 32 MFMA/step, 8 indep
// acc chains); waves 4-7 = service: chunk staging (x load k=0, ws spin k=4,
// gx commit k=8) + attn logits (waves 4,5). Per-step budget: ~550cy MFMA
// issue (128 MFMA/CU, layout-invariant) + ~1050cy barrier-serialized h
// exchange latency -- irreducible at this sync granularity.
// ---------------------------------------------------------------------------
__global__ __attribute__((amdgpu_flat_work_group_size(512, 512), amdgpu_waves_per_eu(2, 2)))
void critic_fused(
    const float* __restrict__ x,
    const float* __restrict__ w_ih, const float* __restrict__ u_ih,
    const float* __restrict__ w_hh, const float* __restrict__ u_hh,
    const float* __restrict__ b_ih, const float* __restrict__ b_hh,
    const float* __restrict__ attn_w, const float* __restrict__ attn_b,
    const float* __restrict__ fc_w, const float* __restrict__ u_fc,
    const float* __restrict__ fc_b,
    float* __restrict__ ws,
    float* __restrict__ out)
{
    const int tid = threadIdx.x;
    const int w   = tid >> 6;          // wave 0..7
    const int l   = tid & 63;          // lane
    const int m   = l & 15;            // A-row / B-col index
    const int q   = l >> 4;            // quad 0..3
    const int b0  = blockIdx.x * RB;
    const int sw  = w - 4;             // service wave id (valid for w>=4)
    const int col = 32 * (w & 3) + (l & 31);  // compute lane's h column
    const int row = l >> 5;            // compute lane's batch row
    const int sub = (l >> 4) & 1;      // compute lane's col-subtile

    // ---- LDS (~141 KB -> 1 block/CU) ----
    __shared__ float4 sSS[2][8][8];                         // std wave-partials per tt
    __shared__ float4 sQQ[2][8][8];
    __shared__ float stdp[2][8];                            // per-c4 std partials
    __shared__ float red[512];                              // sigma scratch
    __shared__ float vv[128];
    __shared__ float sigS[3];                               // sig_ih, sig_hh, sig_fc
    __shared__ __align__(16) _Float16 hs[2][RB][HSP];       // h planes
    __shared__ __align__(16) float gxs[2][CH][RB][GXP];     // gate-interleaved gates_x
    __shared__ __align__(8) float bcast[2][RB];             // beta per row
    __shared__ float Sf[RB];
    __shared__ float part[4][4];                            // FC partials

    // ===== Phase A loads issued FIRST (HBM latency hidden by phase B) =====
    const int c4 = tid & 7;       // c = c4*4 .. c4*4+3
    const int bs = tid >> 3;      // 64 groups of 8 batch rows
    float4 xa[2][8];
#pragma unroll
    for (int tt = 0; tt < 2; ++tt) {
        const int t = 2 * blockIdx.x + tt;
#pragma unroll
        for (int i = 0; i < 8; ++i)
            xa[tt][i] = *reinterpret_cast<const float4*>(
                x + ((size_t)(bs * 8 + i) * TT + t) * CC + c4 * 4);
    }

    // ===== sigma_hh projection in the loads' shadow (L2-bound) =====
    {
        const int c = tid & 127, qq = tid >> 7;
        const float* wp = w_hh + (size_t)(qq * 128) * HH + c;
        const float* up = u_hh + qq * 128;
        float a0 = 0.f, a1 = 0.f, a2 = 0.f, a3 = 0.f;
#pragma unroll 4
        for (int g = 0; g < 128; g += 4) {
            a0 = fmaf(wp[(size_t)(g + 0) * HH], up[g + 0], a0);
            a1 = fmaf(wp[(size_t)(g + 1) * HH], up[g + 1], a1);
            a2 = fmaf(wp[(size_t)(g + 2) * HH], up[g + 2], a2);
            a3 = fmaf(wp[(size_t)(g + 3) * HH], up[g + 3], a3);
        }
        red[tid] = (a0 + a1) + (a2 + a3);
    }

    // ===== Phase A reduction (registers already landed) =====
#pragma unroll
    for (int tt = 0; tt < 2; ++tt) {
        float4 S = make_float4(0.f, 0.f, 0.f, 0.f);
        float4 Q = make_float4(0.f, 0.f, 0.f, 0.f);
#pragma unroll
        for (int i = 0; i < 8; ++i) {
            float4 v = xa[tt][i];
            S.x += v.x; S.y += v.y; S.z += v.z; S.w += v.w;
            Q.x = fmaf(v.x, v.x, Q.x); Q.y = fmaf(v.y, v.y, Q.y);
            Q.z = fmaf(v.z, v.z, Q.z); Q.w = fmaf(v.w, v.w, Q.w);
        }
#pragma unroll
        for (int off = 8; off <= 32; off <<= 1) {
            S.x += __shfl_xor(S.x, off, 64); S.y += __shfl_xor(S.y, off, 64);
            S.z += __shfl_xor(S.z, off, 64); S.w += __shfl_xor(S.w, off, 64);
            Q.x += __shfl_xor(Q.x, off, 64); Q.y += __shfl_xor(Q.y, off, 64);
            Q.z += __shfl_xor(Q.z, off, 64); Q.w += __shfl_xor(Q.w, off, 64);
        }
        if (l < 8) { sSS[tt][w][c4] = S; sQQ[tt][w][c4] = Q; }
    }
    __syncthreads();   // publishes red[] (projection) + sSS/sQQ

    // disjoint groups: tid<128 -> vv combine; tid 384..399 -> std combine
    if (tid < 128) vv[tid] = red[tid] + red[tid + 128] + red[tid + 256] + red[tid + 384];
    if (tid >= 384 && tid < 400) {
        const int tt2 = (tid - 384) >> 3, cc = (tid - 384) & 7;
        float4 St = make_float4(0.f, 0.f, 0.f, 0.f);
        float4 Qt = make_float4(0.f, 0.f, 0.f, 0.f);
#pragma unroll
        for (int i = 0; i < 8; ++i) {
            float4 a = sSS[tt2][i][cc], b4 = sQQ[tt2][i][cc];
            St.x += a.x; St.y += a.y; St.z += a.z; St.w += a.w;
            Qt.x += b4.x; Qt.y += b4.y; Qt.z += b4.z; Qt.w += b4.w;
        }
        float st = 0.f;
#pragma unroll
        for (int i = 0; i < 4; ++i) {
            float s1 = (i == 0) ? St.x : (i == 1) ? St.y : (i == 2) ? St.z : St.w;
            float q1 = (i == 0) ? Qt.x : (i == 1) ? Qt.y : (i == 2) ? Qt.z : Qt.w;
            float mean = s1 / 512.0f;
            float var  = (q1 - 512.0f * mean * mean) / 511.0f;
            st += sqrtf(fmaxf(var, 0.f));
        }
        stdp[tt2][cc] = st;
    }
    __syncthreads();
    // tid 408/409: publish ws[t]; all: square vv for norm reduction
    if (tid >= 408 && tid < 410) {
        const int tt2 = tid - 408;
        float mm = 0.f;
#pragma unroll
        for (int i = 0; i < 8; ++i) mm += stdp[tt2][i];
        __hip_atomic_store(&ws[2 * blockIdx.x + tt2], mm / 32.0f, __ATOMIC_RELAXED,
                           __HIP_MEMORY_SCOPE_AGENT);
    }
    red[tid] = (tid < 128) ? vv[tid] * vv[tid] : 0.f;
    __syncthreads();

    // ===== sigma_hh: norm + W@v =====
    {
        for (int s = 64; s >= 1; s >>= 1) { if (tid < s) red[tid] += red[tid + s]; __syncthreads(); }
        const float nv = sqrtf(red[0]);
        __syncthreads();
        if (tid < 128) vv[tid] = vv[tid] / (nv + EPSF);
        __syncthreads();
        float sq = 0.f;
        float2 vl = *reinterpret_cast<const float2*>(&vv[2 * l]);
#pragma unroll 4
        for (int gi = 0; gi < 64; ++gi) {
            const int g = w * 64 + gi;
            float2 wl = *reinterpret_cast<const float2*>(&w_hh[(size_t)g * HH + 2 * l]);
            float p  = fmaf(wl.x, vl.x, wl.y * vl.y);
            float tot = wave_sum_dpp(p);
            sq = fmaf(tot, tot, sq);
        }
        if (l == 63) red[w] = sq;
        __syncthreads();
        if (tid == 0) {
            float ns2 = 0.f;
            for (int i = 0; i < 8; ++i) ns2 += red[i];
            sigS[1] = ns2 / (sqrtf(ns2) + EPSF);
        }
        __syncthreads();
    }
    // ===== sigma_ih =====
    {
        if (l < CIN) {
            float a0 = 0.f, a1 = 0.f;
#pragma unroll 4
            for (int gi = 0; gi < 64; gi += 2) {
                const int g = w * 64 + gi;
                a0 = fmaf(w_ih[(size_t)(g + 0) * CIN + l], u_ih[g + 0], a0);
                a1 = fmaf(w_ih[(size_t)(g + 1) * CIN + l], u_ih[g + 1], a1);
            }
            red[w * 64 + l] = a0 + a1;
        }
        __syncthreads();
        if (tid < CIN) {
            float v = 0.f;
#pragma unroll
            for (int i = 0; i < 8; ++i) v += red[i * 64 + tid];
            vv[tid] = v;
        }
        __syncthreads();
        if (tid == 0) {
            float n2 = 0.f;
            for (int i = 0; i < CIN; ++i) n2 += vv[i] * vv[i];
            red[400] = sqrtf(n2);
        }
        __syncthreads();
        const float nv = red[400];
        if (tid < CIN) vv[tid] = vv[tid] / (nv + EPSF);
        __syncthreads();
        float vl = (l < CIN) ? vv[l] : 0.f;
        float sq = 0.f;
#pragma unroll 4
        for (int gi = 0; gi < 64; ++gi) {
            const int g = w * 64 + gi;
            float p = (l < CIN) ? w_ih[(size_t)g * CIN + l] * vl : 0.f;
            float tot = wave_sum_dpp(p);
            sq = fmaf(tot, tot, sq);
        }
        if (l == 63) red[w] = sq;
        __syncthreads();
        if (tid == 0) {
            float ns2 = 0.f;
            for (int i = 0; i < 8; ++i) ns2 += red[i];
            sigS[0] = ns2 / (sqrtf(ns2) + EPSF);
        }
        __syncthreads();
    }
    // ===== sigma_fc =====
    {
        red[tid] = (tid < 128) ? fc_w[tid] * fc_w[tid] : 0.f;
        __syncthreads();
        for (int s = 64; s >= 1; s >>= 1) { if (tid < s) red[tid] += red[tid + s]; __syncthreads(); }
        if (tid == 0) {
            float nw2 = red[0];
            float u0  = u_fc[0];
            float nv  = fabsf(u0) * sqrtf(nw2);
            float wv  = u0 * nw2 / (nv + EPSF);
            sigS[2]   = wv * wv / (fabsf(wv) + EPSF);
        }
        __syncthreads();
    }
    const float rih = 1.f / sigS[0];
    const float rhh = 1.f / sigS[1];
    const float rfc = 1.f / sigS[2];
    const float attb = attn_b[0];

    // ================= Phase C: role-split weight conversion =================
    // compute (w<4): BREG[p][sub][kt] = Whh B-frags for cols 32w+16sub+m.
    // service (w>=4): BREG[p][sub][0] aliased as Wih B-frags for its cols.
    half8 BREG[4][2][4];
    float biasg[4][2], w32g[4][2];
    float fcwj = 0.f, aw0 = 0.f, aw1 = 0.f;
    f32x4 zero4 = (f32x4){0.f, 0.f, 0.f, 0.f};
    if (w < 4) {
#pragma unroll
        for (int p = 0; p < 4; ++p)
#pragma unroll
            for (int s = 0; s < 2; ++s) {
                const int g = 128 * p + 32 * w + 16 * s + m;
#pragma unroll
                for (int kt = 0; kt < 4; ++kt) {
                    const float* src = w_hh + (size_t)g * HH + kt * 32 + q * 8;
#pragma unroll
                    for (int i = 0; i < 8; ++i) BREG[p][s][kt][i] = (_Float16)(src[i] * rhh);
                }
            }
#pragma unroll
        for (int p = 0; p < 4; ++p)
#pragma unroll
            for (int s = 0; s < 2; ++s)
#pragma unroll
                for (int kt = 0; kt < 4; ++kt) asm volatile("" : "+v"(BREG[p][s][kt]));
        fcwj = fc_w[col] * rfc;
    } else {
#pragma unroll
        for (int p = 0; p < 4; ++p)
#pragma unroll
            for (int s = 0; s < 2; ++s) {
                const int g = 128 * p + 32 * sw + 16 * s + m;
                const float* src = w_ih + (size_t)g * CIN + q * 8;
#pragma unroll
                for (int i = 0; i < 8; ++i) BREG[p][s][0][i] = (_Float16)(src[i] * rih);
                w32g[p][s]  = w_ih[(size_t)g * CIN + 32] * rih;
                biasg[p][s] = b_ih[g] + b_hh[g];
                asm volatile("" : "+v"(BREG[p][s][0]));
                asm volatile("" : "+v"(biasg[p][s]), "+v"(w32g[p][s]));
            }
        aw0 = attn_w[2 * l];
        aw1 = attn_w[2 * l + 1];
    }
    asm volatile("" : "+v"(zero4));

    // ---- staging: A-row (0..31) = (k,rr) pair; lane m holds rows m, m+16
    //      -> k = 8*mt+(m>>1), rr = m&1. ----
#define STAGE_LOAD(t0_, xr_)                                                   \
    do {                                                                       \
        _Pragma("unroll")                                                      \
        for (int mt = 0; mt < 2; ++mt) {                                       \
            const size_t base =                                                \
                ((size_t)(b0 + (m & 1)) * TT + ((t0_) + 8 * mt + (m >> 1))) *  \
                    CC + q * 8;                                                \
            xr_[mt][0] = *reinterpret_cast<const float4*>(x + base);           \
            xr_[mt][1] = *reinterpret_cast<const float4*>(x + base + 4);       \
        }                                                                      \
    } while (0)

#define STAGE_SPIN(t0_, svr_)                                                  \
    do {                                                                       \
        svr_[0] = load_s(&ws[(t0_) + 2 * q]);                                  \
        svr_[1] = load_s(&ws[(t0_) + 2 * q + 1]);                              \
        svr_[2] = load_s(&ws[(t0_) + 8 + 2 * q]);                              \
        svr_[3] = load_s(&ws[(t0_) + 8 + 2 * q + 1]);                          \
    } while (0)

    // D row (within mt) 4q+j -> k = 8mt+2q+(j>>1), rr = j&1. Lane writes
    // gate-interleaved f32x4 (bias + w32*std folded) for its service cols.
#define STAGE_COMMIT(nb_, xr_, svr_)                                           \
    do {                                                                       \
        _Pragma("unroll")                                                      \
        for (int mt = 0; mt < 2; ++mt) {                                       \
            half8 af = {(_Float16)xr_[mt][0].x, (_Float16)xr_[mt][0].y,        \
                        (_Float16)xr_[mt][0].z, (_Float16)xr_[mt][0].w,        \
                        (_Float16)xr_[mt][1].x, (_Float16)xr_[mt][1].y,        \
                        (_Float16)xr_[mt][1].z, (_Float16)xr_[mt][1].w};       \
            _Pragma("unroll")                                                  \
            for (int s = 0; s < 2; ++s) {                                      \
                f32x4 s0 = MFMA16H(af, BREG[0][s][0], zero4);                  \
                f32x4 s1 = MFMA16H(af, BREG[1][s][0], zero4);                  \
                f32x4 s2 = MFMA16H(af, BREG[2][s][0], zero4);                  \
                f32x4 s3 = MFMA16H(af, BREG[3][s][0], zero4);                  \
                _Pragma("unroll")                                              \
                for (int j = 0; j < 4; ++j) {                                  \
                    const float sv = (j & 2) ? svr_[2 * mt + 1] : svr_[2 * mt];\
                    f32x4 gv;                                                  \
                    gv[0] = s0[j] + fmaf(w32g[0][s], sv, biasg[0][s]);         \
                    gv[1] = s1[j] + fmaf(w32g[1][s], sv, biasg[1][s]);         \
                    gv[2] = s2[j] + fmaf(w32g[2][s], sv, biasg[2][s]);         \
                    gv[3] = s3[j] + fmaf(w32g[3][s], sv, biasg[3][s]);         \
                    *reinterpret_cast<f32x4*>(                                 \
                        &gxs[nb_][8 * mt + 2 * q + (j >> 1)][j & 1]            \
                            [(32 * sw + 16 * s + m) * 4]) = gv;                \
                }                                                              \
            }                                                                  \
        }                                                                      \
    } while (0)

    // ================= Phase E: lstm main =================
    for (int i = tid; i < 2 * RB * HSP; i += 512) (&hs[0][0][0])[i] = (_Float16)0.f;

    float c_st = 0.f, P = 0.f, hprev = 0.f, hpp = 0.f;  // compute lanes
    float Sreg = 0.f;                                    // service 4,5 lane 63
    float4 xr[2][2];
    float svr[4];

    if (w >= 4) {   // chunk-0 staging (spins on ws published by all blocks)
        STAGE_LOAD(0, xr);
        STAGE_SPIN(0, svr);
        STAGE_COMMIT(0, xr, svr);
    }
    __syncthreads();

    for (int tc = 0; tc < NCH; ++tc) {
        const int cb  = tc & 1;
        const int t0n = (tc + 1) * CH;
#pragma unroll 2
        for (int k = 0; k < CH; ++k) {
            const int t  = tc * CH + k;
            const int hb = (t + 1) & 1;
            if (w < 4) {
                // ---------------- compute step ----------------
                half8 ah0 = *(const half8*)&hs[hb][m & 1][0 * 32 + q * 8];
                half8 ah1 = *(const half8*)&hs[hb][m & 1][1 * 32 + q * 8];
                half8 ah2 = *(const half8*)&hs[hb][m & 1][2 * 32 + q * 8];
                half8 ah3 = *(const half8*)&hs[hb][m & 1][3 * 32 + q * 8];
                f32x4 gx4 = *reinterpret_cast<const f32x4*>(&gxs[cb][k][row][col * 4]);
                if (t >= 2) P = fmaf(bcast[(t - 1) & 1][row], hpp, P);
                f32x4 c00 = MFMA16H(ah0, BREG[0][0][0], zero4);
                f32x4 c10 = MFMA16H(ah0, BREG[0][1][0], zero4);
                f32x4 c01 = MFMA16H(ah0, BREG[1][0][0], zero4);
                f32x4 c11 = MFMA16H(ah0, BREG[1][1][0], zero4);
                f32x4 c02 = MFMA16H(ah0, BREG[2][0][0], zero4);
                f32x4 c12 = MFMA16H(ah0, BREG[2][1][0], zero4);
                f32x4 c03 = MFMA16H(ah0, BREG[3][0][0], zero4);
                f32x4 c13 = MFMA16H(ah0, BREG[3][1][0], zero4);
                c00 = MFMA16H(ah1, BREG[0][0][1], c00);
                c10 = MFMA16H(ah1, BREG[0][1][1], c10);
                c01 = MFMA16H(ah1, BREG[1][0][1], c01);
                c11 = MFMA16H(ah1, BREG[1][1][1], c11);
                c02 = MFMA16H(ah1, BREG[2][0][1], c02);
                c12 = MFMA16H(ah1, BREG[2][1][1], c12);
                c03 = MFMA16H(ah1, BREG[3][0][1], c03);
                c13 = MFMA16H(ah1, BREG[3][1][1], c13);
                c00 = MFMA16H(ah2, BREG[0][0][2], c00);
                c10 = MFMA16H(ah2, BREG[0][1][2], c10);
                c01 = MFMA16H(ah2, BREG[1][0][2], c01);
                c11 = MFMA16H(ah2, BREG[1][1][2], c11);
                c02 = MFMA16H(ah2, BREG[2][0][2], c02);
                c12 = MFMA16H(ah2, BREG[2][1][2], c12);
                c03 = MFMA16H(ah2, BREG[3][0][2], c03);
                c13 = MFMA16H(ah2, BREG[3][1][2], c13);
                c00 = MFMA16H(ah3, BREG[0][0][3], c00);
                c10 = MFMA16H(ah3, BREG[0][1][3], c10);
                c01 = MFMA16H(ah3, BREG[1][0][3], c01);
                c11 = MFMA16H(ah3, BREG[1][1][3], c11);
                c02 = MFMA16H(ah3, BREG[2][0][3], c02);
                c12 = MFMA16H(ah3, BREG[2][1][3], c12);
                c03 = MFMA16H(ah3, BREG[3][0][3], c03);
                c13 = MFMA16H(ah3, BREG[3][1][3], c13);
                // D reg j holds batch row j&1; select reg by row, acc by sub.
                float g0 = (sub ? (row ? c10[1] : c10[0]) : (row ? c00[1] : c00[0])) + gx4[0];
                float g1 = (sub ? (row ? c11[1] : c11[0]) : (row ? c01[1] : c01[0])) + gx4[1];
                float g2 = (sub ? (row ? c12[1] : c12[0]) : (row ? c02[1] : c02[0])) + gx4[2];
                float g3 = (sub ? (row ? c13[1] : c13[0]) : (row ? c03[1] : c03[0])) + gx4[3];
                float ig = fsig(g0);
                float fg = fsig(g1);
                float gg = ftanh(g2);
                float og = fsig(g3);
                c_st = fmaf(fg, c_st, ig * gg);
                float hv = og * ftanh(c_st);
                hpp   = hprev;
                hprev = hv;
                hs[t & 1][row][col] = (_Float16)hv;
            } else {
                // ---------------- service step ----------------
                if (sw < 2 && t > 0) {
                    half2v hh = *(const half2v*)&hs[hb][sw][2 * l];
                    float dotp = fmaf(aw0, (float)hh[0], aw1 * (float)hh[1]);
                    float tot = wave_sum_dpp(dotp);
                    if (l == 63) {
                        float beta = __expf(tot + attb);
                        Sreg += beta;
                        bcast[t & 1][sw] = beta;
                    }
                }
                if (tc + 1 < NCH) {
                    if (k == 0) STAGE_LOAD(t0n, xr);
                    else if (k == 4) STAGE_SPIN(t0n, svr);
                    else if (k == 8) STAGE_COMMIT(cb ^ 1, xr, svr);
                }
            }
            BARRIER();
        }
    }

    // ---- epilogue ----
    if (w < 4) P = fmaf(bcast[1][row], hpp, P);
    if (w >= 4 && sw < 2) {
        half2v hh = *(const half2v*)&hs[1][sw][2 * l];
        float dotp = fmaf(aw0, (float)hh[0], aw1 * (float)hh[1]);
        float tot = wave_sum_dpp(dotp);
        if (l == 63) {
            float beta = __expf(tot + attb);
            Sreg += beta;
            bcast[0][sw] = beta;
            Sf[sw] = Sreg;
        }
    }
    __syncthreads();
    if (w < 4) {
        float Pv = fmaf(bcast[0][row], hprev, P);
        float v  = Pv * __builtin_amdgcn_rcpf(Sf[row]) * fcwj;
        float rs = row_sum_dpp(v);
        if ((l & 15) == 15) part[w][q] = rs;   // q: 0,1 -> row0 subtiles; 2,3 -> row1
    }
    __syncthreads();
    if (tid < RB) {
        float a = 0.f;
#pragma unroll
        for (int i = 0; i < 4; ++i) a += part[i][2 * tid] + part[i][2 * tid + 1];
        out[b0 + tid] = a + fc_b[0];
    }
}

// ---------------------------------------------------------------------------
extern "C" void kernel_launch(void* const* d_in, const int* in_sizes, int n_in,
                              void* d_out, int out_size, void* d_ws, size_t ws_size,
                              hipStream_t stream) {
    const float* x      = (const float*)d_in[0];
    const float* w_ih   = (const float*)d_in[1];
    const float* u_ih   = (const float*)d_in[2];
    const float* w_hh   = (const float*)d_in[3];
    const float* u_hh   = (const float*)d_in[4];
    const float* b_ih   = (const float*)d_in[5];
    const float* b_hh   = (const float*)d_in[6];
    const float* attn_w = (const float*)d_in[7];
    const float* attn_b = (const float*)d_in[8];
    const float* fc_w   = (const float*)d_in[9];
    const float* u_fc   = (const float*)d_in[10];
    const float* fc_b   = (const float*)d_in[11];
    float* ws  = (float*)d_ws;
    float* out = (float*)d_out;

    critic_fused<<<BB / RB, 512, 0, stream>>>(x, w_ih, u_ih, w_hh, u_hh, b_ih, b_hh,
                                              attn_w, attn_b, fc_w, u_fc, fc_b, ws, out);
}